// Round 5
// baseline (223.498 us; speedup 1.0000x reference)
//
#include <hip/hip_runtime.h>
#include <hip/hip_bf16.h>

// ---------------- constants ----------------
#define F 128           // hidden width
#define NHID 7          // hidden 128->128 layers
#define BP 64           // points per MLP block
#define LDB 136         // LDS h row stride in ushorts (272 B, 16B-aligned)
#define TRUNC_ 2.0f

// spatial grid: cell size must be >= sqrt(2) (truncation radius)
#define GM 48                  // cells per dimension
#define GM3 (GM * GM * GM)     // 110592
#define GLO (-42.0f)
#define GINV (1.0f / 1.75f)
#define SCAN_BLKS (GM3 / 256)  // 432 scan blocks per grid
#define NGRID 4
#define PACKB 896              // pack_w blocks
#define ZB (NGRID * GM3 / 256) // 1728 zero blocks

typedef __attribute__((ext_vector_type(8))) short short8v;
typedef __attribute__((ext_vector_type(4))) float f32x4;

__device__ inline unsigned short f2bf(float v)
{
    __hip_bfloat16 b = __float2bfloat16(v);
    return __builtin_bit_cast(unsigned short, b);
}
__device__ inline float bf2f(unsigned short u)
{
    unsigned int x = ((unsigned int)u) << 16;
    return __builtin_bit_cast(float, x);
}

// ---------------- prep: pack weights to A-frag(W^T) hi/lo + zero counts ----------------
// pack dest idx = (((m*4 + s)*8 + t)*64 + lane)*8 + j <- W[k][c], k=s*32+(lane>>4)*8+j, c=t*16+(lane&15)
__global__ __launch_bounds__(256) void prep_kernel(
    const float* __restrict__ Wh, const float* __restrict__ Whi,
    unsigned short* __restrict__ whp, unsigned short* __restrict__ wlp,
    int* __restrict__ counts)
{
    int bid = blockIdx.x;
    if (bid < PACKB) {
        int idx = bid * 256 + threadIdx.x;   // 14*4*8*64*8 = 229376 exactly
        int j = idx & 7;
        int l = (idx >> 3) & 63;
        int t = (idx >> 9) & 7;
        int s = (idx >> 12) & 3;
        int m = idx >> 14;                   // 0..13 : mlp*7 + layer
        int k = s * 32 + (l >> 4) * 8 + j;
        int c = t * 16 + (l & 15);
        const float* W = (m < 7 ? Wh + (size_t)m * F * F
                                : Whi + (size_t)(m - 7) * F * F);
        float w = W[k * F + c];
        unsigned short hi = f2bf(w);
        unsigned short lo = f2bf(w - bf2f(hi));
        whp[idx] = hi;
        wlp[idx] = lo;
    } else {
        counts[(bid - PACKB) * 256 + threadIdx.x] = 0;
    }
}

// ---------------- fused double-MLP via MFMA ----------------
// A = pc0 + mlp1(pc0); C = A - mlp2(A)
__global__ __launch_bounds__(512, 4) void mlp_fused_kernel(
    const float* __restrict__ pc0,
    const float* __restrict__ W0a, const float* __restrict__ b0a,
    const float* __restrict__ W0b, const float* __restrict__ b0b,
    const unsigned short* __restrict__ whp,  // packed W^T A-frags hi, 14 layers
    const unsigned short* __restrict__ wlp,  // packed lo
    const float* __restrict__ bha, const float* __restrict__ bhb,
    const float* __restrict__ Wla, const float* __restrict__ bla,
    const float* __restrict__ Wlb, const float* __restrict__ blb,
    float* __restrict__ Aout, float* __restrict__ Cout, int N)
{
    __shared__ unsigned short h0h[BP * LDB];
    __shared__ unsigned short h0l[BP * LDB];
    __shared__ unsigned short h1h[BP * LDB];
    __shared__ unsigned short h1l[BP * LDB];
    __shared__ float Al[BP][4];

    const int tid = threadIdx.x;
    const int lane = tid & 63;
    const int wv = tid >> 6;          // 0..7
    const int pg = wv & 1;            // ptile pair: ptiles {2pg, 2pg+1}
    const int fg = wv >> 1;           // 0..3 -> mtiles {2fg, 2fg+1}
    const int arow = lane & 15;       // A row (f_out) / B col (point)
    const int kg = lane >> 4;         // k-group / C row-group
    const int p0 = blockIdx.x * BP;

    unsigned short* curh = h0h; unsigned short* curl = h0l;
    unsigned short* nxth = h1h; unsigned short* nxtl = h1l;

    for (int M = 0; M < 2; ++M) {
        const float* W0 = M ? W0b : W0a;
        const float* b0 = M ? b0b : b0a;
        const float* bh = M ? bhb : bha;
        const float* Wl = M ? Wlb : Wla;
        const float* bl = M ? blb : bla;
        const float sign = M ? -1.0f : 1.0f;

        // ---- layer 0 (3->128) on VALU: 512 threads, 4 pts each ----
        {
            const int jg = tid & 31;      // 4 cols
            const int pgg = tid >> 5;     // 0..15 -> pts pgg*4..+4
            const int j0 = jg * 4;
            float4 wr0 = *(const float4*)(W0 + 0 * F + j0);
            float4 wr1 = *(const float4*)(W0 + 1 * F + j0);
            float4 wr2 = *(const float4*)(W0 + 2 * F + j0);
            float4 bb0 = *(const float4*)(b0 + j0);
#pragma unroll
            for (int p = 0; p < 4; ++p) {
                int pt = pgg * 4 + p;
                float x0, x1, x2;
                if (M == 0) {
                    int gp = p0 + pt;
                    int cp = gp < N ? gp : N - 1;
                    x0 = pc0[cp * 3 + 0]; x1 = pc0[cp * 3 + 1]; x2 = pc0[cp * 3 + 2];
                } else {
                    x0 = Al[pt][0]; x1 = Al[pt][1]; x2 = Al[pt][2];
                }
                float hx = fmaxf(fmaf(x0, wr0.x, fmaf(x1, wr1.x, fmaf(x2, wr2.x, bb0.x))), 0.f);
                float hy = fmaxf(fmaf(x0, wr0.y, fmaf(x1, wr1.y, fmaf(x2, wr2.y, bb0.y))), 0.f);
                float hz = fmaxf(fmaf(x0, wr0.z, fmaf(x1, wr1.z, fmaf(x2, wr2.z, bb0.z))), 0.f);
                float hw = fmaxf(fmaf(x0, wr0.w, fmaf(x1, wr1.w, fmaf(x2, wr2.w, bb0.w))), 0.f);
                unsigned short a0 = f2bf(hx), a1 = f2bf(hy), a2 = f2bf(hz), a3 = f2bf(hw);
                short4 hv = make_short4((short)a0, (short)a1, (short)a2, (short)a3);
                short4 lv = make_short4((short)f2bf(hx - bf2f(a0)), (short)f2bf(hy - bf2f(a1)),
                                        (short)f2bf(hz - bf2f(a2)), (short)f2bf(hw - bf2f(a3)));
                *(short4*)&curh[pt * LDB + j0] = hv;
                *(short4*)&curl[pt * LDB + j0] = lv;
            }
        }
        __syncthreads();

        // ---- 7 hidden layers via MFMA: C[f_out][pt] = W^T x H ----
        for (int layer = 0; layer < NHID; ++layer) {
            const unsigned short* whL = whp + (size_t)(M * 7 + layer) * 16384;
            const unsigned short* wlL = wlp + (size_t)(M * 7 + layer) * 16384;

            // batch-load ALL weight frags for this wave's 2 mtiles (16 x 16B global)
            short8v wfh[2][4], wfl[2][4];
#pragma unroll
            for (int m = 0; m < 2; ++m) {
#pragma unroll
                for (int s = 0; s < 4; ++s) {
                    int mt = fg * 2 + m;
                    size_t off = ((size_t)((s * 8 + mt) * 64 + lane)) * 8;
                    wfh[m][s] = *(const short8v*)(whL + off);
                    wfl[m][s] = *(const short8v*)(wlL + off);
                }
            }
            // batch-load h frags for this wave's 2 ptiles (16 x ds_read_b128)
            short8v ah[2][4], al[2][4];
#pragma unroll
            for (int p = 0; p < 2; ++p) {
#pragma unroll
                for (int s = 0; s < 4; ++s) {
                    int rb = ((pg * 2 + p) * 16 + arow) * LDB + s * 32 + kg * 8;
                    ah[p][s] = *(const short8v*)&curh[rb];
                    al[p][s] = *(const short8v*)&curl[rb];
                }
            }
            // acc init with bias
            f32x4 acc[2][2];
#pragma unroll
            for (int p = 0; p < 2; ++p)
#pragma unroll
                for (int m = 0; m < 2; ++m)
                    acc[p][m] = *(const f32x4*)&bh[layer * F + (fg * 2 + m) * 16 + kg * 4];

            // pin: all loads issued before MFMA block (prevents load-sinking / VGPR collapse)
            __builtin_amdgcn_sched_barrier(0);

#pragma unroll
            for (int s = 0; s < 4; ++s) {
#pragma unroll
                for (int m = 0; m < 2; ++m) {
#pragma unroll
                    for (int p = 0; p < 2; ++p)
                        acc[p][m] = __builtin_amdgcn_mfma_f32_16x16x32_bf16(wfh[m][s], ah[p][s], acc[p][m], 0, 0, 0);
#pragma unroll
                    for (int p = 0; p < 2; ++p)
                        acc[p][m] = __builtin_amdgcn_mfma_f32_16x16x32_bf16(wfh[m][s], al[p][s], acc[p][m], 0, 0, 0);
#pragma unroll
                    for (int p = 0; p < 2; ++p)
                        acc[p][m] = __builtin_amdgcn_mfma_f32_16x16x32_bf16(wfl[m][s], ah[p][s], acc[p][m], 0, 0, 0);
                }
            }

            // ReLU + hi/lo split + write to next buffer
#pragma unroll
            for (int p = 0; p < 2; ++p) {
#pragma unroll
                for (int m = 0; m < 2; ++m) {
                    float v0 = fmaxf(acc[p][m][0], 0.f), v1 = fmaxf(acc[p][m][1], 0.f);
                    float v2 = fmaxf(acc[p][m][2], 0.f), v3 = fmaxf(acc[p][m][3], 0.f);
                    unsigned short x0 = f2bf(v0), x1 = f2bf(v1), x2 = f2bf(v2), x3 = f2bf(v3);
                    short4 hv = make_short4((short)x0, (short)x1, (short)x2, (short)x3);
                    short4 lv = make_short4((short)f2bf(v0 - bf2f(x0)), (short)f2bf(v1 - bf2f(x1)),
                                            (short)f2bf(v2 - bf2f(x2)), (short)f2bf(v3 - bf2f(x3)));
                    int wadr = ((pg * 2 + p) * 16 + arow) * LDB + (fg * 2 + m) * 16 + kg * 4;
                    *(short4*)&nxth[wadr] = hv;
                    *(short4*)&nxtl[wadr] = lv;
                }
            }
            __syncthreads();
            unsigned short* t;
            t = curh; curh = nxth; nxth = t;
            t = curl; curl = nxtl; nxtl = t;
        }

        // ---- final layer 128->3: 384 threads, 2-way k-split + shfl ----
        if (tid < 384) {
            int pt = tid / 6;
            int rem = tid - pt * 6;
            int c = rem >> 1;
            int ks = rem & 1;
            float acc = 0.f;
            int rb = pt * LDB + ks * 64;
#pragma unroll
            for (int q = 0; q < 8; ++q) {
                short8v h8 = *(const short8v*)&curh[rb + q * 8];
                short8v l8 = *(const short8v*)&curl[rb + q * 8];
#pragma unroll
                for (int j = 0; j < 8; ++j) {
                    float hv = bf2f((unsigned short)h8[j]) + bf2f((unsigned short)l8[j]);
                    acc = fmaf(hv, Wl[(ks * 64 + q * 8 + j) * 3 + c], acc);
                }
            }
            acc += __shfl_down(acc, 1);   // ks=0 lane (even tid) gets full sum
            if (ks == 0) {
                int gp = p0 + pt;
                int cp = gp < N ? gp : N - 1;
                float flow = acc + bl[c];
                if (M == 0) {
                    float val = pc0[cp * 3 + c] + flow;
                    Al[pt][c] = val;
                    if (gp < N) Aout[gp * 3 + c] = val;
                } else {
                    float val = Al[pt][c] - flow;
                    if (gp < N) Cout[gp * 3 + c] = val;
                }
            }
        }
        __syncthreads();
    }
}

// ---------------- spatial grid helpers ----------------
__device__ inline int cell_of(float x, float y, float z)
{
    int cx = (int)floorf((x - GLO) * GINV);
    int cy = (int)floorf((y - GLO) * GINV);
    int cz = (int)floorf((z - GLO) * GINV);
    cx = min(max(cx, 0), GM - 1);
    cy = min(max(cy, 0), GM - 1);
    cz = min(max(cz, 0), GM - 1);
    return (cz * GM + cy) * GM + cx;
}

__device__ inline const float* cloud_ptr(int g, const float* g0, const float* g1,
                                         const float* g2, const float* g3)
{
    return g == 0 ? g0 : (g == 1 ? g1 : (g == 2 ? g2 : g3));
}

__global__ __launch_bounds__(256) void grid_count(
    const float* __restrict__ B, const float* __restrict__ A,
    const float* __restrict__ D, const float* __restrict__ C,
    int* __restrict__ counts, int n)
{
    int g = blockIdx.y;
    const float* P = cloud_ptr(g, B, A, D, C);
    int i = blockIdx.x * 256 + threadIdx.x;
    if (i < n) {
        float x = P[i * 3 + 0], y = P[i * 3 + 1], z = P[i * 3 + 2];
        atomicAdd(&counts[g * GM3 + cell_of(x, y, z)], 1);
    }
}

__global__ __launch_bounds__(256) void scan1(
    const int* __restrict__ counts, int* __restrict__ offs, int* __restrict__ bsum)
{
    int tid = threadIdx.x;
    int i = blockIdx.x * 256 + tid;
    int v = counts[i];
    __shared__ int s[256];
    s[tid] = v;
    __syncthreads();
#pragma unroll
    for (int off = 1; off < 256; off <<= 1) {
        int t = (tid >= off) ? s[tid - off] : 0;
        __syncthreads();
        s[tid] += t;
        __syncthreads();
    }
    offs[i] = s[tid] - v;           // exclusive
    if (tid == 255) bsum[blockIdx.x] = s[255];
}

__global__ __launch_bounds__(256) void scan2(int* __restrict__ bsum)
{
    const int SEG = SCAN_BLKS;      // 432
    int base = blockIdx.x * SEG;
    int t = threadIdx.x;
    int i0 = 2 * t, i1 = 2 * t + 1;
    int e0 = (i0 < SEG) ? bsum[base + i0] : 0;
    int e1 = (i1 < SEG) ? bsum[base + i1] : 0;
    int sum = e0 + e1;
    __shared__ int s[256];
    s[t] = sum;
    __syncthreads();
#pragma unroll
    for (int off = 1; off < 256; off <<= 1) {
        int x = (t >= off) ? s[t - off] : 0;
        __syncthreads();
        s[t] += x;
        __syncthreads();
    }
    int excl = s[t] - sum;
    if (i0 < SEG) bsum[base + i0] = excl;
    if (i1 < SEG) bsum[base + i1] = excl + e0;
}

// scan3 also re-zeros counts (cursors for grid_fill)
__global__ __launch_bounds__(256) void scan3(
    int* __restrict__ offs, const int* __restrict__ bsum, int* __restrict__ counts)
{
    int i = blockIdx.x * 256 + threadIdx.x;
    offs[i] += bsum[blockIdx.x];
    counts[i] = 0;
}

__global__ __launch_bounds__(256) void grid_fill(
    const float* __restrict__ B, const float* __restrict__ A,
    const float* __restrict__ D, const float* __restrict__ C,
    const int* __restrict__ offs, int* __restrict__ counts,
    float4* __restrict__ pts, int n)
{
    int g = blockIdx.y;
    const float* P = cloud_ptr(g, B, A, D, C);
    int i = blockIdx.x * 256 + threadIdx.x;
    if (i < n) {
        float x = P[i * 3 + 0], y = P[i * 3 + 1], z = P[i * 3 + 2];
        int c = g * GM3 + cell_of(x, y, z);
        int slot = offs[c] + atomicAdd(&counts[c], 1);
        pts[(size_t)g * n + slot] = make_float4(x, y, z, 0.f);
    }
}

// ---------------- block sum helper ----------------
__device__ inline float block_sum256(float v)
{
    __shared__ float sws[4];
#pragma unroll
    for (int o = 32; o > 0; o >>= 1) v += __shfl_down(v, o, 64);
    int w = threadIdx.x >> 6;
    if ((threadIdx.x & 63) == 0) sws[w] = v;
    __syncthreads();
    if (threadIdx.x == 0) v = sws[0] + sws[1] + sws[2] + sws[3];
    return v;
}

// per-query truncated NN search fused with block-level sum
__global__ __launch_bounds__(256) void grid_search(
    const float* __restrict__ A, const float* __restrict__ B,
    const float* __restrict__ C, const float* __restrict__ D,
    const int* __restrict__ offs, const int* __restrict__ counts,
    const float4* __restrict__ pts, float* __restrict__ partials, int n)
{
    int d = blockIdx.y;
    const float* Q = cloud_ptr(d, A, B, C, D);
    int g = d;
    int i = blockIdx.x * 256 + threadIdx.x;
    float val = 0.f;
    if (i < n) {
        float qx = Q[i * 3 + 0], qy = Q[i * 3 + 1], qz = Q[i * 3 + 2];
        int cx = min(max((int)floorf((qx - GLO) * GINV), 0), GM - 1);
        int cy = min(max((int)floorf((qy - GLO) * GINV), 0), GM - 1);
        int cz = min(max((int)floorf((qz - GLO) * GINV), 0), GM - 1);
        const int* ofs = offs + (size_t)g * GM3;
        const int* cnt = counts + (size_t)g * GM3;
        const float4* P = pts + (size_t)g * n;
        float mn = 3.4e38f;
        int x0 = max(cx - 1, 0), x1 = min(cx + 1, GM - 1);
#pragma unroll
        for (int dz = -1; dz <= 1; ++dz) {
            int z = cz + dz;
            if ((unsigned)z >= GM) continue;
#pragma unroll
            for (int dy = -1; dy <= 1; ++dy) {
                int y = cy + dy;
                if ((unsigned)y >= GM) continue;
                int rowbase = (z * GM + y) * GM;
                int o = ofs[rowbase + x0];
                int e = ofs[rowbase + x1] + cnt[rowbase + x1];
                for (int k = o; k < e; ++k) {
                    float4 p = P[k];
                    float ddx = qx - p.x, ddy = qy - p.y, ddz = qz - p.z;
                    float dd = fmaf(ddx, ddx, fmaf(ddy, ddy, ddz * ddz));
                    mn = fminf(mn, dd);
                }
            }
        }
        val = (mn < TRUNC_) ? mn : 0.f;
    }
    float bs = block_sum256(val);
    if (threadIdx.x == 0) partials[(size_t)d * gridDim.x + blockIdx.x] = bs;
}

__global__ __launch_bounds__(256) void reduce2_kernel(
    const float* __restrict__ partials, int nb, float* __restrict__ out, float inv)
{
    float s = 0.f;
    for (int i = threadIdx.x; i < nb; i += blockDim.x) s += partials[i];
    float bs = block_sum256(s);
    if (threadIdx.x == 0) out[0] = bs * inv;
}

// ---------------- launch ----------------
extern "C" void kernel_launch(void* const* d_in, const int* in_sizes, int n_in,
                              void* d_out, int out_size, void* d_ws, size_t ws_size,
                              hipStream_t stream)
{
    const float* pc0 = (const float*)d_in[0];
    const float* pc1 = (const float*)d_in[1];
    const float* W0  = (const float*)d_in[2];
    const float* b0  = (const float*)d_in[3];
    const float* Wh  = (const float*)d_in[4];
    const float* bh  = (const float*)d_in[5];
    const float* Wl  = (const float*)d_in[6];
    const float* bl  = (const float*)d_in[7];
    const float* W0i = (const float*)d_in[8];
    const float* b0i = (const float*)d_in[9];
    const float* Whi = (const float*)d_in[10];
    const float* bhi = (const float*)d_in[11];
    const float* Wli = (const float*)d_in[12];
    const float* bli = (const float*)d_in[13];
    float* out = (float*)d_out;

    const int N = in_sizes[0] / 3;   // 20000

    // ws layout (byte offsets)
    char* base = (char*)d_ws;
    float*  A        = (float*)(base + 0);               // 240000
    float*  C        = (float*)(base + 240000);          // 240000
    int*    counts   = (int*)  (base + 480000);          // 1769472
    int*    offs     = (int*)  (base + 2249472);         // 1769472
    int*    bsum     = (int*)  (base + 4018944);         // 6912
    float4* pts      = (float4*)(base + 4025856);        // 1280000
    float*  partials = (float*)(base + 5305856);         // 1264
    unsigned short* whp = (unsigned short*)(base + 5307120); // 458752
    unsigned short* wlp = (unsigned short*)(base + 5765872); // 458752

    const int PB = (N + 255) / 256;        // 79
    const int NP = PB * NGRID;             // 316 partials

    // prep: pack weights + zero counts (merged)
    hipLaunchKernelGGL(prep_kernel, dim3(PACKB + ZB), dim3(256), 0, stream,
                       Wh, Whi, whp, wlp, counts);

    int mlpg = (N + BP - 1) / BP;  // 313
    hipLaunchKernelGGL(mlp_fused_kernel, dim3(mlpg), dim3(512), 0, stream,
                       pc0, W0, b0, W0i, b0i, whp, wlp, bh, bhi,
                       Wl, bl, Wli, bli, A, C, N);

    // build 4 grids: g0=pc1, g1=A, g2=pc0, g3=C
    hipLaunchKernelGGL(grid_count, dim3(PB, NGRID), dim3(256), 0, stream,
                       pc1, A, pc0, C, counts, N);
    hipLaunchKernelGGL(scan1, dim3(ZB), dim3(256), 0, stream, counts, offs, bsum);
    hipLaunchKernelGGL(scan2, dim3(NGRID), dim3(256), 0, stream, bsum);
    hipLaunchKernelGGL(scan3, dim3(ZB), dim3(256), 0, stream, offs, bsum, counts);
    hipLaunchKernelGGL(grid_fill, dim3(PB, NGRID), dim3(256), 0, stream,
                       pc1, A, pc0, C, offs, counts, pts, N);

    // truncated NN search + block sums, all 4 directions
    hipLaunchKernelGGL(grid_search, dim3(PB, NGRID), dim3(256), 0, stream,
                       A, pc1, C, pc0, offs, counts, pts, partials, N);

    hipLaunchKernelGGL(reduce2_kernel, dim3(1), dim3(256), 0, stream,
                       partials, NP, out, 1.0f / (float)N);
}

// Round 6
// 153.967 us; speedup vs baseline: 1.4516x; 1.4516x over previous
//
#include <hip/hip_runtime.h>
#include <hip/hip_bf16.h>

// ---------------- constants ----------------
#define F 128           // hidden width
#define NHID 7          // hidden 128->128 layers
#define BP 64           // points per MLP block
#define TRUNC_ 2.0f

// spatial grid: cell size must be >= sqrt(2) (truncation radius)
#define GM 48                  // cells per dimension
#define GM3 (GM * GM * GM)     // 110592
#define GLO (-42.0f)
#define GINV (1.0f / 1.75f)
#define SCAN_BLKS (GM3 / 256)  // 432 scan blocks per grid
#define NGRID 4
#define PACKB 896              // pack_w blocks
#define ZB (NGRID * GM3 / 256) // 1728 zero blocks

typedef __attribute__((ext_vector_type(8))) short short8v;
typedef __attribute__((ext_vector_type(4))) float f32x4;

__device__ inline unsigned short f2bf(float v)
{
    __hip_bfloat16 b = __float2bfloat16(v);
    return __builtin_bit_cast(unsigned short, b);
}
__device__ inline float bf2f(unsigned short u)
{
    unsigned int x = ((unsigned int)u) << 16;
    return __builtin_bit_cast(float, x);
}

// h LDS layout: [64 rows][128 ushorts], 16B-unit XOR-swizzled by row&7.
// All accesses (b128 read / short4 write) stay inside one 16B unit.
__device__ inline int hsw(int row, int col)   // col in ushorts
{
    return row * 128 + ((((col >> 3) ^ (row & 7)) << 3) | (col & 7));
}

// ---------------- prep: pack weights to A-frag(W^T) hi/lo + zero counts ----------------
// pack dest idx = (((m*4 + s)*8 + t)*64 + lane)*8 + j <- W[k][c], k=s*32+(lane>>4)*8+j, c=t*16+(lane&15)
__global__ __launch_bounds__(256) void prep_kernel(
    const float* __restrict__ Wh, const float* __restrict__ Whi,
    unsigned short* __restrict__ whp, unsigned short* __restrict__ wlp,
    int* __restrict__ counts)
{
    int bid = blockIdx.x;
    if (bid < PACKB) {
        int idx = bid * 256 + threadIdx.x;   // 14*4*8*64*8 = 229376 exactly
        int j = idx & 7;
        int l = (idx >> 3) & 63;
        int t = (idx >> 9) & 7;
        int s = (idx >> 12) & 3;
        int m = idx >> 14;                   // 0..13 : mlp*7 + layer
        int k = s * 32 + (l >> 4) * 8 + j;
        int c = t * 16 + (l & 15);
        const float* W = (m < 7 ? Wh + (size_t)m * F * F
                                : Whi + (size_t)(m - 7) * F * F);
        float w = W[k * F + c];
        unsigned short hi = f2bf(w);
        unsigned short lo = f2bf(w - bf2f(hi));
        whp[idx] = hi;
        wlp[idx] = lo;
    } else {
        counts[(bid - PACKB) * 256 + threadIdx.x] = 0;
    }
}

// ---------------- fused double-MLP via MFMA ----------------
// A = pc0 + mlp1(pc0); C = A - mlp2(A)
__global__ __launch_bounds__(512, 2) void mlp_fused_kernel(
    const float* __restrict__ pc0,
    const float* __restrict__ W0a, const float* __restrict__ b0a,
    const float* __restrict__ W0b, const float* __restrict__ b0b,
    const unsigned short* __restrict__ whp,  // packed W^T A-frags hi, 14 layers
    const unsigned short* __restrict__ wlp,  // packed lo
    const float* __restrict__ bha, const float* __restrict__ bhb,
    const float* __restrict__ Wla, const float* __restrict__ bla,
    const float* __restrict__ Wlb, const float* __restrict__ blb,
    float* __restrict__ Aout, float* __restrict__ Cout, int N)
{
    __shared__ unsigned short h0h[BP * 128];
    __shared__ unsigned short h0l[BP * 128];
    __shared__ unsigned short h1h[BP * 128];
    __shared__ unsigned short h1l[BP * 128];
    __shared__ float Al[BP][4];

    const int tid = threadIdx.x;
    const int lane = tid & 63;
    const int wv = tid >> 6;          // 0..7
    const int pg = wv & 1;            // ptile pair: ptiles {2pg, 2pg+1}
    const int fg = wv >> 1;           // 0..3 -> mtiles {2fg, 2fg+1}
    const int arow = lane & 15;       // A row (f_out) / B col (point)
    const int kg = lane >> 4;         // k-group / C row-group
    const int p0 = blockIdx.x * BP;

    unsigned short* curh = h0h; unsigned short* curl = h0l;
    unsigned short* nxth = h1h; unsigned short* nxtl = h1l;

    for (int M = 0; M < 2; ++M) {
        const float* W0 = M ? W0b : W0a;
        const float* b0 = M ? b0b : b0a;
        const float* bh = M ? bhb : bha;
        const float* Wl = M ? Wlb : Wla;
        const float* bl = M ? blb : bla;

        // ---- layer 0 (3->128) on VALU: 512 threads, 4 pts each ----
        {
            const int jg = tid & 31;      // 4 cols
            const int pgg = tid >> 5;     // 0..15 -> pts pgg*4..+4
            const int j0 = jg * 4;
            float4 wr0 = *(const float4*)(W0 + 0 * F + j0);
            float4 wr1 = *(const float4*)(W0 + 1 * F + j0);
            float4 wr2 = *(const float4*)(W0 + 2 * F + j0);
            float4 bb0 = *(const float4*)(b0 + j0);
#pragma unroll
            for (int p = 0; p < 4; ++p) {
                int pt = pgg * 4 + p;
                float x0, x1, x2;
                if (M == 0) {
                    int gp = p0 + pt;
                    int cp = gp < N ? gp : N - 1;
                    x0 = pc0[cp * 3 + 0]; x1 = pc0[cp * 3 + 1]; x2 = pc0[cp * 3 + 2];
                } else {
                    x0 = Al[pt][0]; x1 = Al[pt][1]; x2 = Al[pt][2];
                }
                float hx = fmaxf(fmaf(x0, wr0.x, fmaf(x1, wr1.x, fmaf(x2, wr2.x, bb0.x))), 0.f);
                float hy = fmaxf(fmaf(x0, wr0.y, fmaf(x1, wr1.y, fmaf(x2, wr2.y, bb0.y))), 0.f);
                float hz = fmaxf(fmaf(x0, wr0.z, fmaf(x1, wr1.z, fmaf(x2, wr2.z, bb0.z))), 0.f);
                float hw = fmaxf(fmaf(x0, wr0.w, fmaf(x1, wr1.w, fmaf(x2, wr2.w, bb0.w))), 0.f);
                unsigned short a0 = f2bf(hx), a1 = f2bf(hy), a2 = f2bf(hz), a3 = f2bf(hw);
                short4 hv = make_short4((short)a0, (short)a1, (short)a2, (short)a3);
                short4 lv = make_short4((short)f2bf(hx - bf2f(a0)), (short)f2bf(hy - bf2f(a1)),
                                        (short)f2bf(hz - bf2f(a2)), (short)f2bf(hw - bf2f(a3)));
                *(short4*)&curh[hsw(pt, j0)] = hv;
                *(short4*)&curl[hsw(pt, j0)] = lv;
            }
        }
        __syncthreads();

        // ---- 7 hidden layers via MFMA: C[f_out][pt] = W^T x H ----
        // stage-pipelined: load k-step s+1 frags while MFMAing k-step s.
#define LOADW(WH, WL, S) \
        { _Pragma("unroll") for (int m = 0; m < 2; ++m) { \
            size_t off = ((size_t)((((S) * 8) + fg * 2 + m) * 64 + lane)) * 8; \
            WH[m] = *(const short8v*)(whL + off); \
            WL[m] = *(const short8v*)(wlL + off); } }
#define LOADH(HH, HL, S) \
        { _Pragma("unroll") for (int p = 0; p < 2; ++p) { \
            int adr = hsw((pg * 2 + p) * 16 + arow, (S) * 32 + kg * 8); \
            HH[p] = *(const short8v*)&curh[adr]; \
            HL[p] = *(const short8v*)&curl[adr]; } }
#define DOMFMA(WH, WL, HH, HL) \
        { _Pragma("unroll") for (int p = 0; p < 2; ++p) \
            _Pragma("unroll") for (int m = 0; m < 2; ++m) \
                acc[p][m] = __builtin_amdgcn_mfma_f32_16x16x32_bf16(WH[m], HH[p], acc[p][m], 0, 0, 0); \
          _Pragma("unroll") for (int p = 0; p < 2; ++p) \
            _Pragma("unroll") for (int m = 0; m < 2; ++m) \
                acc[p][m] = __builtin_amdgcn_mfma_f32_16x16x32_bf16(WH[m], HL[p], acc[p][m], 0, 0, 0); \
          _Pragma("unroll") for (int p = 0; p < 2; ++p) \
            _Pragma("unroll") for (int m = 0; m < 2; ++m) \
                acc[p][m] = __builtin_amdgcn_mfma_f32_16x16x32_bf16(WL[m], HH[p], acc[p][m], 0, 0, 0); }

        for (int layer = 0; layer < NHID; ++layer) {
            const unsigned short* whL = whp + (size_t)(M * 7 + layer) * 16384;
            const unsigned short* wlL = wlp + (size_t)(M * 7 + layer) * 16384;

            f32x4 acc[2][2];
#pragma unroll
            for (int p = 0; p < 2; ++p)
#pragma unroll
                for (int m = 0; m < 2; ++m)
                    acc[p][m] = *(const f32x4*)&bh[layer * F + (fg * 2 + m) * 16 + kg * 4];

            short8v wah[2], wal[2], wbh[2], wbl[2];
            short8v hah[2], hal[2], hbh[2], hbl[2];

            LOADW(wah, wal, 0) LOADH(hah, hal, 0)
            LOADW(wbh, wbl, 1) LOADH(hbh, hbl, 1)
            __builtin_amdgcn_sched_barrier(0);
            DOMFMA(wah, wal, hah, hal)
            LOADW(wah, wal, 2) LOADH(hah, hal, 2)
            __builtin_amdgcn_sched_barrier(0);
            DOMFMA(wbh, wbl, hbh, hbl)
            LOADW(wbh, wbl, 3) LOADH(hbh, hbl, 3)
            __builtin_amdgcn_sched_barrier(0);
            DOMFMA(wah, wal, hah, hal)
            DOMFMA(wbh, wbl, hbh, hbl)

            // ReLU + hi/lo split + swizzled write to next buffer
#pragma unroll
            for (int p = 0; p < 2; ++p) {
#pragma unroll
                for (int m = 0; m < 2; ++m) {
                    float v0 = fmaxf(acc[p][m][0], 0.f), v1 = fmaxf(acc[p][m][1], 0.f);
                    float v2 = fmaxf(acc[p][m][2], 0.f), v3 = fmaxf(acc[p][m][3], 0.f);
                    unsigned short x0 = f2bf(v0), x1 = f2bf(v1), x2 = f2bf(v2), x3 = f2bf(v3);
                    short4 hv = make_short4((short)x0, (short)x1, (short)x2, (short)x3);
                    short4 lv = make_short4((short)f2bf(v0 - bf2f(x0)), (short)f2bf(v1 - bf2f(x1)),
                                            (short)f2bf(v2 - bf2f(x2)), (short)f2bf(v3 - bf2f(x3)));
                    int adr = hsw((pg * 2 + p) * 16 + arow, (fg * 2 + m) * 16 + kg * 4);
                    *(short4*)&nxth[adr] = hv;
                    *(short4*)&nxtl[adr] = lv;
                }
            }
            __syncthreads();
            unsigned short* t;
            t = curh; curh = nxth; nxth = t;
            t = curl; curl = nxtl; nxtl = t;
        }
#undef LOADW
#undef LOADH
#undef DOMFMA

        // ---- final layer 128->3: 384 threads, 2-way k-split + shfl ----
        if (tid < 384) {
            int pt = tid / 6;
            int rem = tid - pt * 6;
            int c = rem >> 1;
            int ks = rem & 1;
            float acc = 0.f;
#pragma unroll
            for (int q = 0; q < 8; ++q) {
                int adr = hsw(pt, ks * 64 + q * 8);
                short8v h8 = *(const short8v*)&curh[adr];
                short8v l8 = *(const short8v*)&curl[adr];
#pragma unroll
                for (int j = 0; j < 8; ++j) {
                    float hv = bf2f((unsigned short)h8[j]) + bf2f((unsigned short)l8[j]);
                    acc = fmaf(hv, Wl[(ks * 64 + q * 8 + j) * 3 + c], acc);
                }
            }
            acc += __shfl_down(acc, 1);   // ks=0 lane (even tid) gets full sum
            if (ks == 0) {
                int gp = p0 + pt;
                int cp = gp < N ? gp : N - 1;
                float flow = acc + bl[c];
                if (M == 0) {
                    float val = pc0[cp * 3 + c] + flow;
                    Al[pt][c] = val;
                    if (gp < N) Aout[gp * 3 + c] = val;
                } else {
                    float val = Al[pt][c] - flow;
                    if (gp < N) Cout[gp * 3 + c] = val;
                }
            }
        }
        __syncthreads();
    }
}

// ---------------- spatial grid helpers ----------------
__device__ inline int cell_of(float x, float y, float z)
{
    int cx = (int)floorf((x - GLO) * GINV);
    int cy = (int)floorf((y - GLO) * GINV);
    int cz = (int)floorf((z - GLO) * GINV);
    cx = min(max(cx, 0), GM - 1);
    cy = min(max(cy, 0), GM - 1);
    cz = min(max(cz, 0), GM - 1);
    return (cz * GM + cy) * GM + cx;
}

__device__ inline const float* cloud_ptr(int g, const float* g0, const float* g1,
                                         const float* g2, const float* g3)
{
    return g == 0 ? g0 : (g == 1 ? g1 : (g == 2 ? g2 : g3));
}

__global__ __launch_bounds__(256) void grid_count(
    const float* __restrict__ B, const float* __restrict__ A,
    const float* __restrict__ D, const float* __restrict__ C,
    int* __restrict__ counts, int n)
{
    int g = blockIdx.y;
    const float* P = cloud_ptr(g, B, A, D, C);
    int i = blockIdx.x * 256 + threadIdx.x;
    if (i < n) {
        float x = P[i * 3 + 0], y = P[i * 3 + 1], z = P[i * 3 + 2];
        atomicAdd(&counts[g * GM3 + cell_of(x, y, z)], 1);
    }
}

__global__ __launch_bounds__(256) void scan1(
    const int* __restrict__ counts, int* __restrict__ offs, int* __restrict__ bsum)
{
    int tid = threadIdx.x;
    int i = blockIdx.x * 256 + tid;
    int v = counts[i];
    __shared__ int s[256];
    s[tid] = v;
    __syncthreads();
#pragma unroll
    for (int off = 1; off < 256; off <<= 1) {
        int t = (tid >= off) ? s[tid - off] : 0;
        __syncthreads();
        s[tid] += t;
        __syncthreads();
    }
    offs[i] = s[tid] - v;           // exclusive
    if (tid == 255) bsum[blockIdx.x] = s[255];
}

__global__ __launch_bounds__(256) void scan2(int* __restrict__ bsum)
{
    const int SEG = SCAN_BLKS;      // 432
    int base = blockIdx.x * SEG;
    int t = threadIdx.x;
    int i0 = 2 * t, i1 = 2 * t + 1;
    int e0 = (i0 < SEG) ? bsum[base + i0] : 0;
    int e1 = (i1 < SEG) ? bsum[base + i1] : 0;
    int sum = e0 + e1;
    __shared__ int s[256];
    s[t] = sum;
    __syncthreads();
#pragma unroll
    for (int off = 1; off < 256; off <<= 1) {
        int x = (t >= off) ? s[t - off] : 0;
        __syncthreads();
        s[t] += x;
        __syncthreads();
    }
    int excl = s[t] - sum;
    if (i0 < SEG) bsum[base + i0] = excl;
    if (i1 < SEG) bsum[base + i1] = excl + e0;
}

// scan3 also re-zeros counts (cursors for grid_fill)
__global__ __launch_bounds__(256) void scan3(
    int* __restrict__ offs, const int* __restrict__ bsum, int* __restrict__ counts)
{
    int i = blockIdx.x * 256 + threadIdx.x;
    offs[i] += bsum[blockIdx.x];
    counts[i] = 0;
}

__global__ __launch_bounds__(256) void grid_fill(
    const float* __restrict__ B, const float* __restrict__ A,
    const float* __restrict__ D, const float* __restrict__ C,
    const int* __restrict__ offs, int* __restrict__ counts,
    float4* __restrict__ pts, int n)
{
    int g = blockIdx.y;
    const float* P = cloud_ptr(g, B, A, D, C);
    int i = blockIdx.x * 256 + threadIdx.x;
    if (i < n) {
        float x = P[i * 3 + 0], y = P[i * 3 + 1], z = P[i * 3 + 2];
        int c = g * GM3 + cell_of(x, y, z);
        int slot = offs[c] + atomicAdd(&counts[c], 1);
        pts[(size_t)g * n + slot] = make_float4(x, y, z, 0.f);
    }
}

// ---------------- block sum helper ----------------
__device__ inline float block_sum256(float v)
{
    __shared__ float sws[4];
#pragma unroll
    for (int o = 32; o > 0; o >>= 1) v += __shfl_down(v, o, 64);
    int w = threadIdx.x >> 6;
    if ((threadIdx.x & 63) == 0) sws[w] = v;
    __syncthreads();
    if (threadIdx.x == 0) v = sws[0] + sws[1] + sws[2] + sws[3];
    return v;
}

// per-query truncated NN search fused with block-level sum
__global__ __launch_bounds__(256) void grid_search(
    const float* __restrict__ A, const float* __restrict__ B,
    const float* __restrict__ C, const float* __restrict__ D,
    const int* __restrict__ offs, const int* __restrict__ counts,
    const float4* __restrict__ pts, float* __restrict__ partials, int n)
{
    int d = blockIdx.y;
    const float* Q = cloud_ptr(d, A, B, C, D);
    int g = d;
    int i = blockIdx.x * 256 + threadIdx.x;
    float val = 0.f;
    if (i < n) {
        float qx = Q[i * 3 + 0], qy = Q[i * 3 + 1], qz = Q[i * 3 + 2];
        int cx = min(max((int)floorf((qx - GLO) * GINV), 0), GM - 1);
        int cy = min(max((int)floorf((qy - GLO) * GINV), 0), GM - 1);
        int cz = min(max((int)floorf((qz - GLO) * GINV), 0), GM - 1);
        const int* ofs = offs + (size_t)g * GM3;
        const int* cnt = counts + (size_t)g * GM3;
        const float4* P = pts + (size_t)g * n;
        float mn = 3.4e38f;
        int x0 = max(cx - 1, 0), x1 = min(cx + 1, GM - 1);
#pragma unroll
        for (int dz = -1; dz <= 1; ++dz) {
            int z = cz + dz;
            if ((unsigned)z >= GM) continue;
#pragma unroll
            for (int dy = -1; dy <= 1; ++dy) {
                int y = cy + dy;
                if ((unsigned)y >= GM) continue;
                int rowbase = (z * GM + y) * GM;
                int o = ofs[rowbase + x0];
                int e = ofs[rowbase + x1] + cnt[rowbase + x1];
                for (int k = o; k < e; ++k) {
                    float4 p = P[k];
                    float ddx = qx - p.x, ddy = qy - p.y, ddz = qz - p.z;
                    float dd = fmaf(ddx, ddx, fmaf(ddy, ddy, ddz * ddz));
                    mn = fminf(mn, dd);
                }
            }
        }
        val = (mn < TRUNC_) ? mn : 0.f;
    }
    float bs = block_sum256(val);
    if (threadIdx.x == 0) partials[(size_t)d * gridDim.x + blockIdx.x] = bs;
}

__global__ __launch_bounds__(256) void reduce2_kernel(
    const float* __restrict__ partials, int nb, float* __restrict__ out, float inv)
{
    float s = 0.f;
    for (int i = threadIdx.x; i < nb; i += blockDim.x) s += partials[i];
    float bs = block_sum256(s);
    if (threadIdx.x == 0) out[0] = bs * inv;
}

// ---------------- launch ----------------
extern "C" void kernel_launch(void* const* d_in, const int* in_sizes, int n_in,
                              void* d_out, int out_size, void* d_ws, size_t ws_size,
                              hipStream_t stream)
{
    const float* pc0 = (const float*)d_in[0];
    const float* pc1 = (const float*)d_in[1];
    const float* W0  = (const float*)d_in[2];
    const float* b0  = (const float*)d_in[3];
    const float* Wh  = (const float*)d_in[4];
    const float* bh  = (const float*)d_in[5];
    const float* Wl  = (const float*)d_in[6];
    const float* bl  = (const float*)d_in[7];
    const float* W0i = (const float*)d_in[8];
    const float* b0i = (const float*)d_in[9];
    const float* Whi = (const float*)d_in[10];
    const float* bhi = (const float*)d_in[11];
    const float* Wli = (const float*)d_in[12];
    const float* bli = (const float*)d_in[13];
    float* out = (float*)d_out;

    const int N = in_sizes[0] / 3;   // 20000

    // ws layout (byte offsets)
    char* base = (char*)d_ws;
    float*  A        = (float*)(base + 0);               // 240000
    float*  C        = (float*)(base + 240000);          // 240000
    int*    counts   = (int*)  (base + 480000);          // 1769472
    int*    offs     = (int*)  (base + 2249472);         // 1769472
    int*    bsum     = (int*)  (base + 4018944);         // 6912
    float4* pts      = (float4*)(base + 4025856);        // 1280000
    float*  partials = (float*)(base + 5305856);         // 1264
    unsigned short* whp = (unsigned short*)(base + 5307120); // 458752
    unsigned short* wlp = (unsigned short*)(base + 5765872); // 458752

    const int PB = (N + 255) / 256;        // 79
    const int NP = PB * NGRID;             // 316 partials

    // prep: pack weights + zero counts (merged)
    hipLaunchKernelGGL(prep_kernel, dim3(PACKB + ZB), dim3(256), 0, stream,
                       Wh, Whi, whp, wlp, counts);

    int mlpg = (N + BP - 1) / BP;  // 313
    hipLaunchKernelGGL(mlp_fused_kernel, dim3(mlpg), dim3(512), 0, stream,
                       pc0, W0, b0, W0i, b0i, whp, wlp, bh, bhi,
                       Wl, bl, Wli, bli, A, C, N);

    // build 4 grids: g0=pc1, g1=A, g2=pc0, g3=C
    hipLaunchKernelGGL(grid_count, dim3(PB, NGRID), dim3(256), 0, stream,
                       pc1, A, pc0, C, counts, N);
    hipLaunchKernelGGL(scan1, dim3(ZB), dim3(256), 0, stream, counts, offs, bsum);
    hipLaunchKernelGGL(scan2, dim3(NGRID), dim3(256), 0, stream, bsum);
    hipLaunchKernelGGL(scan3, dim3(ZB), dim3(256), 0, stream, offs, bsum, counts);
    hipLaunchKernelGGL(grid_fill, dim3(PB, NGRID), dim3(256), 0, stream,
                       pc1, A, pc0, C, offs, counts, pts, N);

    // truncated NN search + block sums, all 4 directions
    hipLaunchKernelGGL(grid_search, dim3(PB, NGRID), dim3(256), 0, stream,
                       A, pc1, C, pc0, offs, counts, pts, partials, N);

    hipLaunchKernelGGL(reduce2_kernel, dim3(1), dim3(256), 0, stream,
                       partials, NP, out, 1.0f / (float)N);
}

// Round 7
// 129.386 us; speedup vs baseline: 1.7274x; 1.1900x over previous
//
#include <hip/hip_runtime.h>
#include <hip/hip_bf16.h>

// ---------------- constants ----------------
#define F 128           // hidden width
#define NHID 7          // hidden 128->128 layers
#define BP 64           // points per MLP block
#define TRUNC_ 2.0f

// spatial grid: cell size must be >= sqrt(2) (truncation radius)
#define GM 48                  // cells per dimension
#define GM3 (GM * GM * GM)     // 110592
#define GLO (-42.0f)
#define GINV (1.0f / 1.75f)
#define SCAN_BLKS (GM3 / 256)  // 432 scan blocks per grid
#define NGRID 4
#define PACKB 896              // pack_w blocks
#define ZB (NGRID * GM3 / 256) // 1728 zero blocks

typedef __attribute__((ext_vector_type(8))) short short8v;
typedef __attribute__((ext_vector_type(4))) float f32x4;

__device__ inline unsigned short f2bf(float v)
{
    __hip_bfloat16 b = __float2bfloat16(v);
    return __builtin_bit_cast(unsigned short, b);
}
__device__ inline float bf2f(unsigned short u)
{
    unsigned int x = ((unsigned int)u) << 16;
    return __builtin_bit_cast(float, x);
}

// h LDS layout: [64 rows][128 ushorts], 16B-unit XOR-swizzled by row&7.
__device__ inline int hsw(int row, int col)   // col in ushorts
{
    return row * 128 + ((((col >> 3) ^ (row & 7)) << 3) | (col & 7));
}

// barrier WITHOUT vmcnt drain: LDS writes visible, global prefetches stay in flight
__device__ inline void barrier_nd()
{
    asm volatile("s_waitcnt lgkmcnt(0)" ::: "memory");
    __builtin_amdgcn_s_barrier();
}

// ---------------- prep: pack weights (A-frag W^T hi/lo), WlT, zero counts ----------------
// pack dest idx = (((m*4 + s)*8 + t)*64 + lane)*8 <- W[k][c], k=s*32+(lane>>4)*8+j, c=t*16+(lane&15)
__global__ __launch_bounds__(256) void prep_kernel(
    const float* __restrict__ Wh, const float* __restrict__ Whi,
    const float* __restrict__ Wl, const float* __restrict__ Wli,
    unsigned short* __restrict__ whp, unsigned short* __restrict__ wlp,
    float* __restrict__ wlt, int* __restrict__ counts)
{
    int bid = blockIdx.x;
    int t = threadIdx.x;
    if (bid < PACKB) {
        int idx = bid * 256 + t;             // 14*4*8*64*8 = 229376 exactly
        int j = idx & 7;
        int l = (idx >> 3) & 63;
        int tt = (idx >> 9) & 7;
        int s = (idx >> 12) & 3;
        int m = idx >> 14;                   // 0..13 : mlp*7 + layer
        int k = s * 32 + (l >> 4) * 8 + j;
        int c = tt * 16 + (l & 15);
        const float* W = (m < 7 ? Wh + (size_t)m * F * F
                                : Whi + (size_t)(m - 7) * F * F);
        float w = W[k * F + c];
        unsigned short hi = f2bf(w);
        unsigned short lo = f2bf(w - bf2f(hi));
        whp[idx] = hi;
        wlp[idx] = lo;
    } else if (bid < PACKB + ZB) {
        counts[(bid - PACKB) * 256 + t] = 0;
    } else {
        // WlT[mlp][c][k] = Wl[k*3+c], 2*3*128 = 768 floats
#pragma unroll
        for (int r = 0; r < 3; ++r) {
            int e = r * 256 + t;
            int mI = e / 384;
            int rem = e - mI * 384;
            int c = rem >> 7;
            int k = rem & 127;
            const float* W = mI ? Wli : Wl;
            wlt[e] = W[k * 3 + c];
        }
    }
}

// ---------------- spatial grid cell ----------------
__device__ inline int cell_of(float x, float y, float z)
{
    int cx = (int)floorf((x - GLO) * GINV);
    int cy = (int)floorf((y - GLO) * GINV);
    int cz = (int)floorf((z - GLO) * GINV);
    cx = min(max(cx, 0), GM - 1);
    cy = min(max(cy, 0), GM - 1);
    cz = min(max(cz, 0), GM - 1);
    return (cz * GM + cy) * GM + cx;
}

// ---------------- fused double-MLP via MFMA + grid counting epilogue ----------------
// A = pc0 + mlp1(pc0); C = A - mlp2(A); counts for all 4 clouds
__global__ __launch_bounds__(512, 2) void mlp_fused_kernel(
    const float* __restrict__ pc0, const float* __restrict__ pc1,
    const float* __restrict__ W0a, const float* __restrict__ b0a,
    const float* __restrict__ W0b, const float* __restrict__ b0b,
    const unsigned short* __restrict__ whp,  // packed W^T A-frags hi, 14 layers
    const unsigned short* __restrict__ wlp,  // packed lo
    const float* __restrict__ bha, const float* __restrict__ bhb,
    const float* __restrict__ wlt,           // WlT [2][3][128]
    const float* __restrict__ bla, const float* __restrict__ blb,
    float* __restrict__ Aout, float* __restrict__ Cout,
    int* __restrict__ counts, int N)
{
    __shared__ unsigned short hX[BP * 128];
    __shared__ unsigned short hY[BP * 128];
    __shared__ float Al[BP][4];
    __shared__ float Cl[BP][4];

    const int tid = threadIdx.x;
    const int lane = tid & 63;
    const int wv = tid >> 6;          // 0..7
    const int pg = wv & 1;            // ptile pair {2pg, 2pg+1}
    const int fg = wv >> 1;           // mtile pair {2fg, 2fg+1}
    const int arow = lane & 15;
    const int kg = lane >> 4;
    const int p0 = blockIdx.x * BP;

    unsigned short* cur = hX;
    unsigned short* nxt = hY;

    short8v w0h[2], w0l[2], w1h[2], w1l[2], w2h[2], w2l[2], w3h[2], w3l[2];
    short8v ha[2], hb[2];

#define LW(D, LI, S) { _Pragma("unroll") for (int m = 0; m < 2; ++m) { \
        size_t off = ((size_t)(((LI) * 4 + (S)) * 8 + fg * 2 + m) * 64 + lane) * 8; \
        D##h[m] = *(const short8v*)(whp + off); \
        D##l[m] = *(const short8v*)(wlp + off); } }
#define LH(D, S) { _Pragma("unroll") for (int p = 0; p < 2; ++p) \
        D[p] = *(const short8v*)&cur[hsw((pg * 2 + p) * 16 + arow, (S) * 32 + kg * 8)]; }
#define MM(WH, WL, H) { \
    _Pragma("unroll") for (int p = 0; p < 2; ++p) \
    _Pragma("unroll") for (int m = 0; m < 2; ++m) \
        acc[p][m] = __builtin_amdgcn_mfma_f32_16x16x32_bf16(WH[m], H[p], acc[p][m], 0, 0, 0); \
    _Pragma("unroll") for (int p = 0; p < 2; ++p) \
    _Pragma("unroll") for (int m = 0; m < 2; ++m) \
        acc[p][m] = __builtin_amdgcn_mfma_f32_16x16x32_bf16(WL[m], H[p], acc[p][m], 0, 0, 0); }

    // issue first layer's s0/s1 weight loads immediately (hide under layer 0)
    LW(w0, 0, 0)
    LW(w1, 0, 1)
    __builtin_amdgcn_sched_barrier(0);

    for (int M = 0; M < 2; ++M) {
        const float* W0 = M ? W0b : W0a;
        const float* b0 = M ? b0b : b0a;
        const float* bh = M ? bhb : bha;
        const float* bl = M ? blb : bla;

        // ---- layer 0 (3->128) on VALU: 512 threads, 4 pts each ----
        {
            const int jg = tid & 31;
            const int pgg = tid >> 5;
            const int j0 = jg * 4;
            float4 wr0 = *(const float4*)(W0 + 0 * F + j0);
            float4 wr1 = *(const float4*)(W0 + 1 * F + j0);
            float4 wr2 = *(const float4*)(W0 + 2 * F + j0);
            float4 bb0 = *(const float4*)(b0 + j0);
#pragma unroll
            for (int p = 0; p < 4; ++p) {
                int pt = pgg * 4 + p;
                float x0, x1, x2;
                if (M == 0) {
                    int gp = p0 + pt;
                    int cp = gp < N ? gp : N - 1;
                    x0 = pc0[cp * 3 + 0]; x1 = pc0[cp * 3 + 1]; x2 = pc0[cp * 3 + 2];
                } else {
                    x0 = Al[pt][0]; x1 = Al[pt][1]; x2 = Al[pt][2];
                }
                float hx = fmaxf(fmaf(x0, wr0.x, fmaf(x1, wr1.x, fmaf(x2, wr2.x, bb0.x))), 0.f);
                float hy = fmaxf(fmaf(x0, wr0.y, fmaf(x1, wr1.y, fmaf(x2, wr2.y, bb0.y))), 0.f);
                float hz = fmaxf(fmaf(x0, wr0.z, fmaf(x1, wr1.z, fmaf(x2, wr2.z, bb0.z))), 0.f);
                float hw = fmaxf(fmaf(x0, wr0.w, fmaf(x1, wr1.w, fmaf(x2, wr2.w, bb0.w))), 0.f);
                short4 hv = make_short4((short)f2bf(hx), (short)f2bf(hy),
                                        (short)f2bf(hz), (short)f2bf(hw));
                *(short4*)&cur[hsw(pt, j0)] = hv;
            }
        }
        barrier_nd();

        // ---- 7 hidden layers, W hi/lo x H bf16, cross-layer W prefetch ----
        for (int l = 0; l < NHID; ++l) {
            const int L = M * 7 + l;
            f32x4 acc[2][2];
#pragma unroll
            for (int p = 0; p < 2; ++p)
#pragma unroll
                for (int m = 0; m < 2; ++m)
                    acc[p][m] = *(const f32x4*)&bh[l * F + (fg * 2 + m) * 16 + kg * 4];

            LH(ha, 0) LH(hb, 1)
            __builtin_amdgcn_sched_barrier(0);
            MM(w0h, w0l, ha)
            LW(w2, L, 2) LH(ha, 2)
            __builtin_amdgcn_sched_barrier(0);
            MM(w1h, w1l, hb)
            LW(w3, L, 3) LH(hb, 3)
            __builtin_amdgcn_sched_barrier(0);
            MM(w2h, w2l, ha)
            {
                const int Ln = (L + 1 < 14) ? (L + 1) : 13;   // prefetch next layer
                LW(w0, Ln, 0) LW(w1, Ln, 1)
            }
            __builtin_amdgcn_sched_barrier(0);
            MM(w3h, w3l, hb)

            // ReLU + bf16 + swizzled write to next buffer
#pragma unroll
            for (int p = 0; p < 2; ++p)
#pragma unroll
                for (int m = 0; m < 2; ++m) {
                    float v0 = fmaxf(acc[p][m][0], 0.f), v1 = fmaxf(acc[p][m][1], 0.f);
                    float v2 = fmaxf(acc[p][m][2], 0.f), v3 = fmaxf(acc[p][m][3], 0.f);
                    short4 hv = make_short4((short)f2bf(v0), (short)f2bf(v1),
                                            (short)f2bf(v2), (short)f2bf(v3));
                    *(short4*)&nxt[hsw((pg * 2 + p) * 16 + arow,
                                       (fg * 2 + m) * 16 + kg * 4)] = hv;
                }
            barrier_nd();
            unsigned short* tsw = cur; cur = nxt; nxt = tsw;
        }

        // ---- final layer 128->3: 384 threads, 2-way k-split + shfl ----
        if (tid < 384) {
            int pt = tid / 6;
            int rem = tid - pt * 6;
            int c = rem >> 1;
            int ks = rem & 1;
            const float* wl = wlt + M * 384 + c * 128 + ks * 64;
            float acc = 0.f;
#pragma unroll
            for (int q = 0; q < 8; ++q) {
                short8v h8 = *(const short8v*)&cur[hsw(pt, ks * 64 + q * 8)];
                float4 wa = *(const float4*)(wl + q * 8);
                float4 wb = *(const float4*)(wl + q * 8 + 4);
                acc = fmaf(bf2f((unsigned short)h8[0]), wa.x, acc);
                acc = fmaf(bf2f((unsigned short)h8[1]), wa.y, acc);
                acc = fmaf(bf2f((unsigned short)h8[2]), wa.z, acc);
                acc = fmaf(bf2f((unsigned short)h8[3]), wa.w, acc);
                acc = fmaf(bf2f((unsigned short)h8[4]), wb.x, acc);
                acc = fmaf(bf2f((unsigned short)h8[5]), wb.y, acc);
                acc = fmaf(bf2f((unsigned short)h8[6]), wb.z, acc);
                acc = fmaf(bf2f((unsigned short)h8[7]), wb.w, acc);
            }
            acc += __shfl_down(acc, 1);   // pairs (even,odd) never straddle a wave
            if (ks == 0) {
                int gp = p0 + pt;
                int cp = gp < N ? gp : N - 1;
                float flow = acc + bl[c];
                if (M == 0) {
                    float val = pc0[cp * 3 + c] + flow;
                    Al[pt][c] = val;
                    if (gp < N) Aout[gp * 3 + c] = val;
                } else {
                    float val = Al[pt][c] - flow;
                    Cl[pt][c] = val;
                    if (gp < N) Cout[gp * 3 + c] = val;
                }
            }
        }
        barrier_nd();
    }
#undef LW
#undef LH
#undef MM

    // ---- epilogue: grid counts for all 4 clouds (block's own 64 points) ----
    if (tid < BP) {
        int gp = p0 + tid;
        if (gp < N) {
            atomicAdd(&counts[1 * GM3 + cell_of(Al[tid][0], Al[tid][1], Al[tid][2])], 1);
            atomicAdd(&counts[3 * GM3 + cell_of(Cl[tid][0], Cl[tid][1], Cl[tid][2])], 1);
            atomicAdd(&counts[0 * GM3 + cell_of(pc1[gp * 3 + 0], pc1[gp * 3 + 1], pc1[gp * 3 + 2])], 1);
            atomicAdd(&counts[2 * GM3 + cell_of(pc0[gp * 3 + 0], pc0[gp * 3 + 1], pc0[gp * 3 + 2])], 1);
        }
    }
}

// ---------------- grid build ----------------
__device__ inline const float* cloud_ptr(int g, const float* g0, const float* g1,
                                         const float* g2, const float* g3)
{
    return g == 0 ? g0 : (g == 1 ? g1 : (g == 2 ? g2 : g3));
}

__global__ __launch_bounds__(256) void scan1(
    const int* __restrict__ counts, int* __restrict__ offs, int* __restrict__ bsum)
{
    int tid = threadIdx.x;
    int i = blockIdx.x * 256 + tid;
    int v = counts[i];
    __shared__ int s[256];
    s[tid] = v;
    __syncthreads();
#pragma unroll
    for (int off = 1; off < 256; off <<= 1) {
        int t = (tid >= off) ? s[tid - off] : 0;
        __syncthreads();
        s[tid] += t;
        __syncthreads();
    }
    offs[i] = s[tid] - v;           // exclusive
    if (tid == 255) bsum[blockIdx.x] = s[255];
}

// scan2+scan3 fused: each block computes its segment-local prefix of bsum itself,
// adds it, and re-zeros counts (cursors for grid_fill)
__global__ __launch_bounds__(256) void scan23(
    int* __restrict__ offs, const int* __restrict__ bsum, int* __restrict__ counts)
{
    int seg = blockIdx.x / SCAN_BLKS;
    int pos = blockIdx.x - seg * SCAN_BLKS;
    const int* bs = bsum + seg * SCAN_BLKS;
    int t = threadIdx.x;
    int v = 0;
    if (t < pos) v = bs[t];
    if (t + 256 < pos) v += bs[t + 256];
    __shared__ int red[4];
#pragma unroll
    for (int o = 32; o > 0; o >>= 1) v += __shfl_down(v, o, 64);
    if ((t & 63) == 0) red[t >> 6] = v;
    __syncthreads();
    int prefix = red[0] + red[1] + red[2] + red[3];
    int i = blockIdx.x * 256 + t;
    offs[i] += prefix;
    counts[i] = 0;
}

__global__ __launch_bounds__(256) void grid_fill(
    const float* __restrict__ B, const float* __restrict__ A,
    const float* __restrict__ D, const float* __restrict__ C,
    const int* __restrict__ offs, int* __restrict__ counts,
    float4* __restrict__ pts, int n)
{
    int g = blockIdx.y;
    const float* P = cloud_ptr(g, B, A, D, C);
    int i = blockIdx.x * 256 + threadIdx.x;
    if (i < n) {
        float x = P[i * 3 + 0], y = P[i * 3 + 1], z = P[i * 3 + 2];
        int c = g * GM3 + cell_of(x, y, z);
        int slot = offs[c] + atomicAdd(&counts[c], 1);
        pts[(size_t)g * n + slot] = make_float4(x, y, z, 0.f);
    }
}

// ---------------- block sum helper ----------------
__device__ inline float block_sum256(float v)
{
    __shared__ float sws[4];
#pragma unroll
    for (int o = 32; o > 0; o >>= 1) v += __shfl_down(v, o, 64);
    int w = threadIdx.x >> 6;
    if ((threadIdx.x & 63) == 0) sws[w] = v;
    __syncthreads();
    if (threadIdx.x == 0) v = sws[0] + sws[1] + sws[2] + sws[3];
    return v;
}

// per-query truncated NN search fused with block-level sum
__global__ __launch_bounds__(256) void grid_search(
    const float* __restrict__ A, const float* __restrict__ B,
    const float* __restrict__ C, const float* __restrict__ D,
    const int* __restrict__ offs, const int* __restrict__ counts,
    const float4* __restrict__ pts, float* __restrict__ partials, int n)
{
    int d = blockIdx.y;
    const float* Q = cloud_ptr(d, A, B, C, D);
    int g = d;
    int i = blockIdx.x * 256 + threadIdx.x;
    float val = 0.f;
    if (i < n) {
        float qx = Q[i * 3 + 0], qy = Q[i * 3 + 1], qz = Q[i * 3 + 2];
        int cx = min(max((int)floorf((qx - GLO) * GINV), 0), GM - 1);
        int cy = min(max((int)floorf((qy - GLO) * GINV), 0), GM - 1);
        int cz = min(max((int)floorf((qz - GLO) * GINV), 0), GM - 1);
        const int* ofs = offs + (size_t)g * GM3;
        const int* cnt = counts + (size_t)g * GM3;
        const float4* P = pts + (size_t)g * n;
        float mn = 3.4e38f;
        int x0 = max(cx - 1, 0), x1 = min(cx + 1, GM - 1);
#pragma unroll
        for (int dz = -1; dz <= 1; ++dz) {
            int z = cz + dz;
            if ((unsigned)z >= GM) continue;
#pragma unroll
            for (int dy = -1; dy <= 1; ++dy) {
                int y = cy + dy;
                if ((unsigned)y >= GM) continue;
                int rowbase = (z * GM + y) * GM;
                int o = ofs[rowbase + x0];
                int e = ofs[rowbase + x1] + cnt[rowbase + x1];
                for (int k = o; k < e; ++k) {
                    float4 p = P[k];
                    float ddx = qx - p.x, ddy = qy - p.y, ddz = qz - p.z;
                    float dd = fmaf(ddx, ddx, fmaf(ddy, ddy, ddz * ddz));
                    mn = fminf(mn, dd);
                }
            }
        }
        val = (mn < TRUNC_) ? mn : 0.f;
    }
    float bs = block_sum256(val);
    if (threadIdx.x == 0) partials[(size_t)d * gridDim.x + blockIdx.x] = bs;
}

__global__ __launch_bounds__(256) void reduce2_kernel(
    const float* __restrict__ partials, int nb, float* __restrict__ out, float inv)
{
    float s = 0.f;
    for (int i = threadIdx.x; i < nb; i += blockDim.x) s += partials[i];
    float bs = block_sum256(s);
    if (threadIdx.x == 0) out[0] = bs * inv;
}

// ---------------- launch ----------------
extern "C" void kernel_launch(void* const* d_in, const int* in_sizes, int n_in,
                              void* d_out, int out_size, void* d_ws, size_t ws_size,
                              hipStream_t stream)
{
    const float* pc0 = (const float*)d_in[0];
    const float* pc1 = (const float*)d_in[1];
    const float* W0  = (const float*)d_in[2];
    const float* b0  = (const float*)d_in[3];
    const float* Wh  = (const float*)d_in[4];
    const float* bh  = (const float*)d_in[5];
    const float* Wl  = (const float*)d_in[6];
    const float* bl  = (const float*)d_in[7];
    const float* W0i = (const float*)d_in[8];
    const float* b0i = (const float*)d_in[9];
    const float* Whi = (const float*)d_in[10];
    const float* bhi = (const float*)d_in[11];
    const float* Wli = (const float*)d_in[12];
    const float* bli = (const float*)d_in[13];
    float* out = (float*)d_out;

    const int N = in_sizes[0] / 3;   // 20000

    // ws layout (byte offsets)
    char* base = (char*)d_ws;
    float*  A        = (float*)(base + 0);               // 240000
    float*  C        = (float*)(base + 240000);          // 240000
    int*    counts   = (int*)  (base + 480000);          // 1769472
    int*    offs     = (int*)  (base + 2249472);         // 1769472
    int*    bsum     = (int*)  (base + 4018944);         // 6912
    float4* pts      = (float4*)(base + 4025856);        // 1280000
    float*  partials = (float*)(base + 5305856);         // 1264
    unsigned short* whp = (unsigned short*)(base + 5307120); // 458752
    unsigned short* wlp = (unsigned short*)(base + 5765872); // 458752
    float*  wlt      = (float*)(base + 6224624);         // 3072

    const int PB = (N + 255) / 256;        // 79
    const int NP = PB * NGRID;             // 316 partials

    // prep: pack weights + WlT + zero counts
    hipLaunchKernelGGL(prep_kernel, dim3(PACKB + ZB + 1), dim3(256), 0, stream,
                       Wh, Whi, Wl, Wli, whp, wlp, wlt, counts);

    int mlpg = (N + BP - 1) / BP;  // 313
    hipLaunchKernelGGL(mlp_fused_kernel, dim3(mlpg), dim3(512), 0, stream,
                       pc0, pc1, W0, b0, W0i, b0i, whp, wlp, bh, bhi,
                       wlt, bl, bli, A, C, counts, N);

    // grids: g0=pc1, g1=A, g2=pc0, g3=C (counts already done in mlp epilogue)
    hipLaunchKernelGGL(scan1, dim3(ZB), dim3(256), 0, stream, counts, offs, bsum);
    hipLaunchKernelGGL(scan23, dim3(ZB), dim3(256), 0, stream, offs, bsum, counts);
    hipLaunchKernelGGL(grid_fill, dim3(PB, NGRID), dim3(256), 0, stream,
                       pc1, A, pc0, C, offs, counts, pts, N);

    // truncated NN search + block sums, all 4 directions
    hipLaunchKernelGGL(grid_search, dim3(PB, NGRID), dim3(256), 0, stream,
                       A, pc1, C, pc0, offs, counts, pts, partials, N);

    hipLaunchKernelGGL(reduce2_kernel, dim3(1), dim3(256), 0, stream,
                       partials, NP, out, 1.0f / (float)N);
}

// Round 8
// 97.608 us; speedup vs baseline: 2.2898x; 1.3256x over previous
//
#include <hip/hip_runtime.h>
#include <hip/hip_bf16.h>

// ---------------- constants ----------------
#define F 128           // hidden width
#define NHID 7          // hidden 128->128 layers
#define BP 80           // points per MLP block (250 blocks exactly, <=1/CU)
#define NPT 5           // ptiles per wave
#define TRUNC_ 2.0f

// spatial grid: cell size must be >= sqrt(2) (truncation radius)
#define GM 32                  // cells per dimension
#define GM3 (GM * GM * GM)     // 32768
#define GLO (-28.0f)
#define GINV (1.0f / 1.75f)
#define SCAN_BLKS (GM3 / 256)  // 128 scan blocks per grid
#define NGRID 4
#define PACKB 896              // pack_w blocks
#define ZB (NGRID * GM3 / 256) // 512 zero/scan blocks

typedef __attribute__((ext_vector_type(8))) short short8v;
typedef __attribute__((ext_vector_type(4))) float f32x4;

__device__ inline unsigned short f2bf(float v)
{
    __hip_bfloat16 b = __float2bfloat16(v);
    return __builtin_bit_cast(unsigned short, b);
}
__device__ inline float bf2f(unsigned short u)
{
    unsigned int x = ((unsigned int)u) << 16;
    return __builtin_bit_cast(float, x);
}

// h LDS layout: [80 rows][128 ushorts], 16B-unit XOR-swizzled by row&7.
__device__ inline int hsw(int row, int col)   // col in ushorts
{
    return row * 128 + ((((col >> 3) ^ (row & 7)) << 3) | (col & 7));
}

// barrier WITHOUT vmcnt drain: LDS writes visible, global prefetches stay in flight
__device__ inline void barrier_nd()
{
    asm volatile("s_waitcnt lgkmcnt(0)" ::: "memory");
    __builtin_amdgcn_s_barrier();
}

// ---------------- prep: pack weights (A-frag W^T hi/lo), WlT, zero counts+done ----------------
__global__ __launch_bounds__(256) void prep_kernel(
    const float* __restrict__ Wh, const float* __restrict__ Whi,
    const float* __restrict__ Wl, const float* __restrict__ Wli,
    unsigned short* __restrict__ whp, unsigned short* __restrict__ wlp,
    float* __restrict__ wlt, int* __restrict__ counts, unsigned int* __restrict__ done)
{
    int bid = blockIdx.x;
    int t = threadIdx.x;
    if (bid < PACKB) {
        int idx = bid * 256 + t;             // 14*4*8*64*8 = 229376 exactly
        int j = idx & 7;
        int l = (idx >> 3) & 63;
        int tt = (idx >> 9) & 7;
        int s = (idx >> 12) & 3;
        int m = idx >> 14;                   // 0..13 : mlp*7 + layer
        int k = s * 32 + (l >> 4) * 8 + j;
        int c = tt * 16 + (l & 15);
        const float* W = (m < 7 ? Wh + (size_t)m * F * F
                                : Whi + (size_t)(m - 7) * F * F);
        float w = W[k * F + c];
        unsigned short hi = f2bf(w);
        unsigned short lo = f2bf(w - bf2f(hi));
        whp[idx] = hi;
        wlp[idx] = lo;
    } else if (bid < PACKB + ZB) {
        counts[(bid - PACKB) * 256 + t] = 0;
    } else {
        // WlT[mlp][c][k] = Wl[k*3+c], 2*3*128 = 768 floats
#pragma unroll
        for (int r = 0; r < 3; ++r) {
            int e = r * 256 + t;
            int mI = e / 384;
            int rem = e - mI * 384;
            int c = rem >> 7;
            int k = rem & 127;
            const float* W = mI ? Wli : Wl;
            wlt[e] = W[k * 3 + c];
        }
        if (t == 0) *done = 0u;
    }
}

// ---------------- spatial grid cell ----------------
__device__ inline int cell_of(float x, float y, float z)
{
    int cx = (int)floorf((x - GLO) * GINV);
    int cy = (int)floorf((y - GLO) * GINV);
    int cz = (int)floorf((z - GLO) * GINV);
    cx = min(max(cx, 0), GM - 1);
    cy = min(max(cy, 0), GM - 1);
    cz = min(max(cz, 0), GM - 1);
    return (cz * GM + cy) * GM + cx;
}

// ---------------- fused double-MLP via MFMA + grid counting epilogue ----------------
// A = pc0 + mlp1(pc0); C = A - mlp2(A); counts for all 4 clouds.
// 8 waves; wave wv owns mtile wv (16 f_out) x all 5 ptiles. No weight duplication.
__global__ __launch_bounds__(512, 2) void mlp_fused_kernel(
    const float* __restrict__ pc0, const float* __restrict__ pc1,
    const float* __restrict__ W0a, const float* __restrict__ b0a,
    const float* __restrict__ W0b, const float* __restrict__ b0b,
    const unsigned short* __restrict__ whp,  // packed W^T A-frags hi, 14 layers
    const unsigned short* __restrict__ wlp,  // packed lo
    const float* __restrict__ bha, const float* __restrict__ bhb,
    const float* __restrict__ wlt,           // WlT [2][3][128]
    const float* __restrict__ bla, const float* __restrict__ blb,
    float* __restrict__ Aout, float* __restrict__ Cout,
    int* __restrict__ counts, int N)
{
    __shared__ unsigned short hX[BP * 128];
    __shared__ unsigned short hY[BP * 128];
    __shared__ float Al[BP][4];
    __shared__ float Cl[BP][4];

    const int tid = threadIdx.x;
    const int lane = tid & 63;
    const int wv = tid >> 6;          // 0..7 == mtile
    const int arow = lane & 15;       // A row (f_out) / B col (point)
    const int kg = lane >> 4;         // k-group / C row-group
    const int p0 = blockIdx.x * BP;

    unsigned short* cur = hX;
    unsigned short* nxt = hY;

    short8v wAhi, wAlo, wBhi, wBlo;
    short8v hA[NPT], hB[NPT];

#define LW(WHI, WLO, LI, S) { \
        size_t off = ((size_t)(((LI) * 4 + (S)) * 8 + wv) * 64 + lane) * 8; \
        WHI = *(const short8v*)(whp + off); \
        WLO = *(const short8v*)(wlp + off); }
#define LH(D, S) { _Pragma("unroll") for (int p = 0; p < NPT; ++p) \
        D[p] = *(const short8v*)&cur[hsw(p * 16 + arow, (S) * 32 + kg * 8)]; }
#define MM(WHI, WLO, H) { \
    _Pragma("unroll") for (int p = 0; p < NPT; ++p) \
        acc[p] = __builtin_amdgcn_mfma_f32_16x16x32_bf16(WHI, H[p], acc[p], 0, 0, 0); \
    _Pragma("unroll") for (int p = 0; p < NPT; ++p) \
        acc[p] = __builtin_amdgcn_mfma_f32_16x16x32_bf16(WLO, H[p], acc[p], 0, 0, 0); }

    // preload layer 0's s0/s1 weight frags (hide under layer-0 VALU)
    LW(wAhi, wAlo, 0, 0)
    LW(wBhi, wBlo, 0, 1)
    __builtin_amdgcn_sched_barrier(0);

    for (int M = 0; M < 2; ++M) {
        const float* W0 = M ? W0b : W0a;
        const float* b0 = M ? b0b : b0a;
        const float* bh = M ? bhb : bha;
        const float* bl = M ? blb : bla;

        // ---- layer 0 (3->128) on VALU: 512 threads, 5 pts each ----
        {
            const int jg = tid & 31;
            const int pgg = tid >> 5;     // 0..15 -> pts pgg*5..+5
            const int j0 = jg * 4;
            float4 wr0 = *(const float4*)(W0 + 0 * F + j0);
            float4 wr1 = *(const float4*)(W0 + 1 * F + j0);
            float4 wr2 = *(const float4*)(W0 + 2 * F + j0);
            float4 bb0 = *(const float4*)(b0 + j0);
#pragma unroll
            for (int p = 0; p < 5; ++p) {
                int pt = pgg * 5 + p;
                float x0, x1, x2;
                if (M == 0) {
                    int gp = p0 + pt;
                    int cp = gp < N ? gp : N - 1;
                    x0 = pc0[cp * 3 + 0]; x1 = pc0[cp * 3 + 1]; x2 = pc0[cp * 3 + 2];
                } else {
                    x0 = Al[pt][0]; x1 = Al[pt][1]; x2 = Al[pt][2];
                }
                float hx = fmaxf(fmaf(x0, wr0.x, fmaf(x1, wr1.x, fmaf(x2, wr2.x, bb0.x))), 0.f);
                float hy = fmaxf(fmaf(x0, wr0.y, fmaf(x1, wr1.y, fmaf(x2, wr2.y, bb0.y))), 0.f);
                float hz = fmaxf(fmaf(x0, wr0.z, fmaf(x1, wr1.z, fmaf(x2, wr2.z, bb0.z))), 0.f);
                float hw = fmaxf(fmaf(x0, wr0.w, fmaf(x1, wr1.w, fmaf(x2, wr2.w, bb0.w))), 0.f);
                short4 hv = make_short4((short)f2bf(hx), (short)f2bf(hy),
                                        (short)f2bf(hz), (short)f2bf(hw));
                *(short4*)&cur[hsw(pt, j0)] = hv;
            }
        }
        barrier_nd();

        // ---- 7 hidden layers, W hi/lo x H bf16, 2-stage ping-pong + x-layer prefetch ----
        for (int l = 0; l < NHID; ++l) {
            const int L = M * 7 + l;
            const int Ln = (L + 1 < 14) ? (L + 1) : 13;
            f32x4 acc[NPT];
            {
                float4 b4 = *(const float4*)&bh[l * F + wv * 16 + kg * 4];
#pragma unroll
                for (int p = 0; p < NPT; ++p)
                    acc[p] = (f32x4){b4.x, b4.y, b4.z, b4.w};
            }

            LH(hA, 0) LH(hB, 1)
            __builtin_amdgcn_sched_barrier(0);
            MM(wAhi, wAlo, hA)              // s0
            LW(wAhi, wAlo, L, 2) LH(hA, 2)
            __builtin_amdgcn_sched_barrier(0);
            MM(wBhi, wBlo, hB)              // s1
            LW(wBhi, wBlo, L, 3) LH(hB, 3)
            __builtin_amdgcn_sched_barrier(0);
            MM(wAhi, wAlo, hA)              // s2
            LW(wAhi, wAlo, Ln, 0)           // prefetch next layer s0
            __builtin_amdgcn_sched_barrier(0);
            MM(wBhi, wBlo, hB)              // s3
            LW(wBhi, wBlo, Ln, 1)           // prefetch next layer s1

            // ReLU + bf16 + swizzled write
#pragma unroll
            for (int p = 0; p < NPT; ++p) {
                float v0 = fmaxf(acc[p][0], 0.f), v1 = fmaxf(acc[p][1], 0.f);
                float v2 = fmaxf(acc[p][2], 0.f), v3 = fmaxf(acc[p][3], 0.f);
                short4 hv = make_short4((short)f2bf(v0), (short)f2bf(v1),
                                        (short)f2bf(v2), (short)f2bf(v3));
                *(short4*)&nxt[hsw(p * 16 + arow, wv * 16 + kg * 4)] = hv;
            }
            barrier_nd();
            unsigned short* tsw = cur; cur = nxt; nxt = tsw;
        }

        // ---- final layer 128->3: 240 threads, full-k, 4 rotating accs ----
        if (tid < 240) {
            int pt = tid / 3;
            int c = tid - 3 * pt;
            const float* wl = wlt + M * 384 + c * 128;
            float a0 = 0.f, a1 = 0.f, a2 = 0.f, a3 = 0.f;
#pragma unroll
            for (int q = 0; q < 16; ++q) {
                short8v h8 = *(const short8v*)&cur[hsw(pt, q * 8)];
                float4 wa = *(const float4*)(wl + q * 8);
                float4 wb = *(const float4*)(wl + q * 8 + 4);
                a0 = fmaf(bf2f((unsigned short)h8[0]), wa.x, a0);
                a1 = fmaf(bf2f((unsigned short)h8[1]), wa.y, a1);
                a2 = fmaf(bf2f((unsigned short)h8[2]), wa.z, a2);
                a3 = fmaf(bf2f((unsigned short)h8[3]), wa.w, a3);
                a0 = fmaf(bf2f((unsigned short)h8[4]), wb.x, a0);
                a1 = fmaf(bf2f((unsigned short)h8[5]), wb.y, a1);
                a2 = fmaf(bf2f((unsigned short)h8[6]), wb.z, a2);
                a3 = fmaf(bf2f((unsigned short)h8[7]), wb.w, a3);
            }
            float flow = ((a0 + a1) + (a2 + a3)) + bl[c];
            int gp = p0 + pt;
            int cp = gp < N ? gp : N - 1;
            if (M == 0) {
                float val = pc0[cp * 3 + c] + flow;
                Al[pt][c] = val;
                if (gp < N) Aout[gp * 3 + c] = val;
            } else {
                float val = Al[pt][c] - flow;
                Cl[pt][c] = val;
                if (gp < N) Cout[gp * 3 + c] = val;
            }
        }
        barrier_nd();
    }
#undef LW
#undef LH
#undef MM

    // ---- epilogue: grid counts for all 4 clouds (block's own points) ----
    if (tid < BP) {
        int gp = p0 + tid;
        if (gp < N) {
            atomicAdd(&counts[1 * GM3 + cell_of(Al[tid][0], Al[tid][1], Al[tid][2])], 1);
            atomicAdd(&counts[3 * GM3 + cell_of(Cl[tid][0], Cl[tid][1], Cl[tid][2])], 1);
            atomicAdd(&counts[0 * GM3 + cell_of(pc1[gp * 3 + 0], pc1[gp * 3 + 1], pc1[gp * 3 + 2])], 1);
            atomicAdd(&counts[2 * GM3 + cell_of(pc0[gp * 3 + 0], pc0[gp * 3 + 1], pc0[gp * 3 + 2])], 1);
        }
    }
}

// ---------------- grid build ----------------
__device__ inline const float* cloud_ptr(int g, const float* g0, const float* g1,
                                         const float* g2, const float* g3)
{
    return g == 0 ? g0 : (g == 1 ? g1 : (g == 2 ? g2 : g3));
}

__global__ __launch_bounds__(256) void scan1(
    const int* __restrict__ counts, int* __restrict__ offs, int* __restrict__ bsum)
{
    int tid = threadIdx.x;
    int i = blockIdx.x * 256 + tid;
    int v = counts[i];
    __shared__ int s[256];
    s[tid] = v;
    __syncthreads();
#pragma unroll
    for (int off = 1; off < 256; off <<= 1) {
        int t = (tid >= off) ? s[tid - off] : 0;
        __syncthreads();
        s[tid] += t;
        __syncthreads();
    }
    offs[i] = s[tid] - v;           // exclusive
    if (tid == 255) bsum[blockIdx.x] = s[255];
}

// scan2+scan3 fused: per-block segment prefix of bsum (SCAN_BLKS=128 <= 256),
// add to offs, re-zero counts (cursors for grid_fill)
__global__ __launch_bounds__(256) void scan23(
    int* __restrict__ offs, const int* __restrict__ bsum, int* __restrict__ counts)
{
    int seg = blockIdx.x / SCAN_BLKS;
    int pos = blockIdx.x - seg * SCAN_BLKS;
    const int* bs = bsum + seg * SCAN_BLKS;
    int t = threadIdx.x;
    int v = (t < pos) ? bs[t] : 0;
    __shared__ int red[4];
#pragma unroll
    for (int o = 32; o > 0; o >>= 1) v += __shfl_down(v, o, 64);
    if ((t & 63) == 0) red[t >> 6] = v;
    __syncthreads();
    int prefix = red[0] + red[1] + red[2] + red[3];
    int i = blockIdx.x * 256 + t;
    offs[i] += prefix;
    counts[i] = 0;
}

__global__ __launch_bounds__(256) void grid_fill(
    const float* __restrict__ B, const float* __restrict__ A,
    const float* __restrict__ D, const float* __restrict__ C,
    const int* __restrict__ offs, int* __restrict__ counts,
    float4* __restrict__ pts, int n)
{
    int g = blockIdx.y;
    const float* P = cloud_ptr(g, B, A, D, C);
    int i = blockIdx.x * 256 + threadIdx.x;
    if (i < n) {
        float x = P[i * 3 + 0], y = P[i * 3 + 1], z = P[i * 3 + 2];
        int c = g * GM3 + cell_of(x, y, z);
        int slot = offs[c] + atomicAdd(&counts[c], 1);
        pts[(size_t)g * n + slot] = make_float4(x, y, z, 0.f);
    }
}

// ---------------- block sum helper ----------------
__device__ inline float block_sum256(float v)
{
    __shared__ float sws[4];
#pragma unroll
    for (int o = 32; o > 0; o >>= 1) v += __shfl_down(v, o, 64);
    int w = threadIdx.x >> 6;
    if ((threadIdx.x & 63) == 0) sws[w] = v;
    __syncthreads();
    if (threadIdx.x == 0) v = sws[0] + sws[1] + sws[2] + sws[3];
    return v;
}

// per-query truncated NN search + block sum + fused final reduction (last block)
__global__ __launch_bounds__(256) void grid_search(
    const float* __restrict__ A, const float* __restrict__ B,
    const float* __restrict__ C, const float* __restrict__ D,
    const int* __restrict__ offs, const int* __restrict__ counts,
    const float4* __restrict__ pts, float* __restrict__ partials,
    unsigned int* __restrict__ done, float* __restrict__ out, float inv, int n)
{
    int d = blockIdx.y;
    const float* Q = cloud_ptr(d, A, B, C, D);
    int g = d;
    int i = blockIdx.x * 256 + threadIdx.x;
    float val = 0.f;
    if (i < n) {
        float qx = Q[i * 3 + 0], qy = Q[i * 3 + 1], qz = Q[i * 3 + 2];
        int cx = min(max((int)floorf((qx - GLO) * GINV), 0), GM - 1);
        int cy = min(max((int)floorf((qy - GLO) * GINV), 0), GM - 1);
        int cz = min(max((int)floorf((qz - GLO) * GINV), 0), GM - 1);
        const int* ofs = offs + (size_t)g * GM3;
        const int* cnt = counts + (size_t)g * GM3;
        const float4* P = pts + (size_t)g * n;
        float mn = 3.4e38f;
        int x0 = max(cx - 1, 0), x1 = min(cx + 1, GM - 1);
#pragma unroll
        for (int dz = -1; dz <= 1; ++dz) {
            int z = cz + dz;
            if ((unsigned)z >= GM) continue;
#pragma unroll
            for (int dy = -1; dy <= 1; ++dy) {
                int y = cy + dy;
                if ((unsigned)y >= GM) continue;
                int rowbase = (z * GM + y) * GM;
                int o = ofs[rowbase + x0];
                int e = ofs[rowbase + x1] + cnt[rowbase + x1];
                for (int k = o; k < e; ++k) {
                    float4 p = P[k];
                    float ddx = qx - p.x, ddy = qy - p.y, ddz = qz - p.z;
                    float dd = fmaf(ddx, ddx, fmaf(ddy, ddy, ddz * ddz));
                    mn = fminf(mn, dd);
                }
            }
        }
        val = (mn < TRUNC_) ? mn : 0.f;
    }
    float bs = block_sum256(val);

    __shared__ int lastflag;
    if (threadIdx.x == 0) {
        atomicExch(&partials[(size_t)d * gridDim.x + blockIdx.x], bs);
        __threadfence();
        unsigned v = atomicAdd(done, 1u);
        lastflag = (v == (unsigned)(NGRID * gridDim.x - 1)) ? 1 : 0;
    }
    __syncthreads();
    if (lastflag) {
        int NPt = NGRID * gridDim.x;
        float s = 0.f;
        for (int j = threadIdx.x; j < NPt; j += 256)
            s += atomicAdd(&partials[j], 0.0f);   // device-scope read
        __syncthreads();
        float tot = block_sum256(s);
        if (threadIdx.x == 0) out[0] = tot * inv;
    }
}

// ---------------- launch ----------------
extern "C" void kernel_launch(void* const* d_in, const int* in_sizes, int n_in,
                              void* d_out, int out_size, void* d_ws, size_t ws_size,
                              hipStream_t stream)
{
    const float* pc0 = (const float*)d_in[0];
    const float* pc1 = (const float*)d_in[1];
    const float* W0  = (const float*)d_in[2];
    const float* b0  = (const float*)d_in[3];
    const float* Wh  = (const float*)d_in[4];
    const float* bh  = (const float*)d_in[5];
    const float* Wl  = (const float*)d_in[6];
    const float* bl  = (const float*)d_in[7];
    const float* W0i = (const float*)d_in[8];
    const float* b0i = (const float*)d_in[9];
    const float* Whi = (const float*)d_in[10];
    const float* bhi = (const float*)d_in[11];
    const float* Wli = (const float*)d_in[12];
    const float* bli = (const float*)d_in[13];
    float* out = (float*)d_out;

    const int N = in_sizes[0] / 3;   // 20000

    // ws layout (byte offsets)
    char* base = (char*)d_ws;
    float*  A        = (float*)(base + 0);               // 240000
    float*  C        = (float*)(base + 240000);          // 240000
    int*    counts   = (int*)  (base + 480000);          // 524288
    int*    offs     = (int*)  (base + 1004288);         // 524288
    int*    bsum     = (int*)  (base + 1528576);         // 4096
    float4* pts      = (float4*)(base + 1532672);        // 1280000
    float*  partials = (float*)(base + 2812672);         // 2048
    unsigned int* done = (unsigned int*)(base + 2814720);// 16
    unsigned short* whp = (unsigned short*)(base + 2814736); // 458752
    unsigned short* wlp = (unsigned short*)(base + 3273488); // 458752
    float*  wlt      = (float*)(base + 3732240);         // 3072

    const int PB = (N + 255) / 256;        // 79

    // prep: pack weights + WlT + zero counts + zero done-counter
    hipLaunchKernelGGL(prep_kernel, dim3(PACKB + ZB + 1), dim3(256), 0, stream,
                       Wh, Whi, Wl, Wli, whp, wlp, wlt, counts, done);

    int mlpg = (N + BP - 1) / BP;  // 250
    hipLaunchKernelGGL(mlp_fused_kernel, dim3(mlpg), dim3(512), 0, stream,
                       pc0, pc1, W0, b0, W0i, b0i, whp, wlp, bh, bhi,
                       wlt, bl, bli, A, C, counts, N);

    // grids: g0=pc1, g1=A, g2=pc0, g3=C (counts already done in mlp epilogue)
    hipLaunchKernelGGL(scan1, dim3(ZB), dim3(256), 0, stream, counts, offs, bsum);
    hipLaunchKernelGGL(scan23, dim3(ZB), dim3(256), 0, stream, offs, bsum, counts);
    hipLaunchKernelGGL(grid_fill, dim3(PB, NGRID), dim3(256), 0, stream,
                       pc1, A, pc0, C, offs, counts, pts, N);

    // truncated NN search + block sums + fused final reduce
    hipLaunchKernelGGL(grid_search, dim3(PB, NGRID), dim3(256), 0, stream,
                       A, pc1, C, pc0, offs, counts, pts, partials, done, out,
                       1.0f / (float)N, N);
}

// Round 9
// 77.903 us; speedup vs baseline: 2.8689x; 1.2529x over previous
//
#include <hip/hip_runtime.h>
#include <hip/hip_bf16.h>

// ---------------- constants ----------------
#define F 128           // hidden width
#define NHID 7          // hidden 128->128 layers
#define BP 80           // points per MLP block (250 blocks exactly, <=1/CU)
#define NPT 5           // ptiles per wave
#define TRUNC_ 2.0f

// spatial grid: cell size must be >= sqrt(2) (truncation radius)
#define GM 32                  // cells per dimension
#define GM3 (GM * GM * GM)     // 32768
#define GLO (-28.0f)
#define GINV (1.0f / 1.75f)
#define SCAN_BLKS (GM3 / 256)  // 128 scan blocks per grid
#define NGRID 4
#define PACKB 896              // pack_w blocks
#define ZB (NGRID * GM3 / 256) // 512 zero/scan blocks
#define BQ 128                 // queries per search block (2 threads/query)

typedef __attribute__((ext_vector_type(8))) short short8v;
typedef __attribute__((ext_vector_type(4))) float f32x4;

__device__ inline unsigned short f2bf(float v)
{
    __hip_bfloat16 b = __float2bfloat16(v);
    return __builtin_bit_cast(unsigned short, b);
}
__device__ inline float bf2f(unsigned short u)
{
    unsigned int x = ((unsigned int)u) << 16;
    return __builtin_bit_cast(float, x);
}

// h LDS layout: [80 rows][128 ushorts], 16B-unit XOR-swizzled by row&7.
__device__ inline int hsw(int row, int col)   // col in ushorts
{
    return row * 128 + ((((col >> 3) ^ (row & 7)) << 3) | (col & 7));
}

// barrier WITHOUT vmcnt drain: LDS writes visible, global prefetches stay in flight
__device__ inline void barrier_nd()
{
    asm volatile("s_waitcnt lgkmcnt(0)" ::: "memory");
    __builtin_amdgcn_s_barrier();
}

// ---------------- prep: pack weights (A-frag W^T hi/lo), WlT, zero counts+done ----------------
__global__ __launch_bounds__(256) void prep_kernel(
    const float* __restrict__ Wh, const float* __restrict__ Whi,
    const float* __restrict__ Wl, const float* __restrict__ Wli,
    unsigned short* __restrict__ whp, unsigned short* __restrict__ wlp,
    float* __restrict__ wlt, int* __restrict__ counts, unsigned int* __restrict__ done)
{
    int bid = blockIdx.x;
    int t = threadIdx.x;
    if (bid < PACKB) {
        int idx = bid * 256 + t;             // 14*4*8*64*8 = 229376 exactly
        int j = idx & 7;
        int l = (idx >> 3) & 63;
        int tt = (idx >> 9) & 7;
        int s = (idx >> 12) & 3;
        int m = idx >> 14;                   // 0..13 : mlp*7 + layer
        int k = s * 32 + (l >> 4) * 8 + j;
        int c = tt * 16 + (l & 15);
        const float* W = (m < 7 ? Wh + (size_t)m * F * F
                                : Whi + (size_t)(m - 7) * F * F);
        float w = W[k * F + c];
        unsigned short hi = f2bf(w);
        unsigned short lo = f2bf(w - bf2f(hi));
        whp[idx] = hi;
        wlp[idx] = lo;
    } else if (bid < PACKB + ZB) {
        counts[(bid - PACKB) * 256 + t] = 0;
    } else {
        // WlT[mlp][c][k] = Wl[k*3+c], 2*3*128 = 768 floats
#pragma unroll
        for (int r = 0; r < 3; ++r) {
            int e = r * 256 + t;
            int mI = e / 384;
            int rem = e - mI * 384;
            int c = rem >> 7;
            int k = rem & 127;
            const float* W = mI ? Wli : Wl;
            wlt[e] = W[k * 3 + c];
        }
        if (t == 0) *done = 0u;
    }
}

// ---------------- spatial grid cell ----------------
__device__ inline int cell_of(float x, float y, float z)
{
    int cx = (int)floorf((x - GLO) * GINV);
    int cy = (int)floorf((y - GLO) * GINV);
    int cz = (int)floorf((z - GLO) * GINV);
    cx = min(max(cx, 0), GM - 1);
    cy = min(max(cy, 0), GM - 1);
    cz = min(max(cz, 0), GM - 1);
    return (cz * GM + cy) * GM + cx;
}

// ---------------- fused double-MLP via MFMA + grid counting epilogue ----------------
// A = pc0 + mlp1(pc0); C = A - mlp2(A); counts for all 4 clouds.
// 8 waves; wave wv owns mtile wv (16 f_out) x all 5 ptiles. No weight duplication.
__global__ __launch_bounds__(512, 2) void mlp_fused_kernel(
    const float* __restrict__ pc0, const float* __restrict__ pc1,
    const float* __restrict__ W0a, const float* __restrict__ b0a,
    const float* __restrict__ W0b, const float* __restrict__ b0b,
    const unsigned short* __restrict__ whp,  // packed W^T A-frags hi, 14 layers
    const unsigned short* __restrict__ wlp,  // packed lo
    const float* __restrict__ bha, const float* __restrict__ bhb,
    const float* __restrict__ wlt,           // WlT [2][3][128]
    const float* __restrict__ bla, const float* __restrict__ blb,
    float* __restrict__ Aout, float* __restrict__ Cout,
    int* __restrict__ counts, int N)
{
    __shared__ unsigned short hX[BP * 128];
    __shared__ unsigned short hY[BP * 128];
    __shared__ float Al[BP][4];
    __shared__ float Cl[BP][4];

    const int tid = threadIdx.x;
    const int lane = tid & 63;
    const int wv = tid >> 6;          // 0..7 == mtile
    const int arow = lane & 15;       // A row (f_out) / B col (point)
    const int kg = lane >> 4;         // k-group / C row-group
    const int p0 = blockIdx.x * BP;

    unsigned short* cur = hX;
    unsigned short* nxt = hY;

    short8v wAhi, wAlo, wBhi, wBlo;
    short8v hA[NPT], hB[NPT];

#define LW(WHI, WLO, LI, S) { \
        size_t off = ((size_t)(((LI) * 4 + (S)) * 8 + wv) * 64 + lane) * 8; \
        WHI = *(const short8v*)(whp + off); \
        WLO = *(const short8v*)(wlp + off); }
#define LH(D, S) { _Pragma("unroll") for (int p = 0; p < NPT; ++p) \
        D[p] = *(const short8v*)&cur[hsw(p * 16 + arow, (S) * 32 + kg * 8)]; }
#define MM(WHI, WLO, H) { \
    _Pragma("unroll") for (int p = 0; p < NPT; ++p) \
        acc[p] = __builtin_amdgcn_mfma_f32_16x16x32_bf16(WHI, H[p], acc[p], 0, 0, 0); \
    _Pragma("unroll") for (int p = 0; p < NPT; ++p) \
        acc[p] = __builtin_amdgcn_mfma_f32_16x16x32_bf16(WLO, H[p], acc[p], 0, 0, 0); }

    // preload layer 0's s0/s1 weight frags (hide under layer-0 VALU)
    LW(wAhi, wAlo, 0, 0)
    LW(wBhi, wBlo, 0, 1)
    __builtin_amdgcn_sched_barrier(0);

    for (int M = 0; M < 2; ++M) {
        const float* W0 = M ? W0b : W0a;
        const float* b0 = M ? b0b : b0a;
        const float* bh = M ? bhb : bha;
        const float* bl = M ? blb : bla;

        // ---- layer 0 (3->128) on VALU: 512 threads, 5 pts each ----
        {
            const int jg = tid & 31;
            const int pgg = tid >> 5;     // 0..15 -> pts pgg*5..+5
            const int j0 = jg * 4;
            float4 wr0 = *(const float4*)(W0 + 0 * F + j0);
            float4 wr1 = *(const float4*)(W0 + 1 * F + j0);
            float4 wr2 = *(const float4*)(W0 + 2 * F + j0);
            float4 bb0 = *(const float4*)(b0 + j0);
#pragma unroll
            for (int p = 0; p < 5; ++p) {
                int pt = pgg * 5 + p;
                float x0, x1, x2;
                if (M == 0) {
                    int gp = p0 + pt;
                    int cp = gp < N ? gp : N - 1;
                    x0 = pc0[cp * 3 + 0]; x1 = pc0[cp * 3 + 1]; x2 = pc0[cp * 3 + 2];
                } else {
                    x0 = Al[pt][0]; x1 = Al[pt][1]; x2 = Al[pt][2];
                }
                float hx = fmaxf(fmaf(x0, wr0.x, fmaf(x1, wr1.x, fmaf(x2, wr2.x, bb0.x))), 0.f);
                float hy = fmaxf(fmaf(x0, wr0.y, fmaf(x1, wr1.y, fmaf(x2, wr2.y, bb0.y))), 0.f);
                float hz = fmaxf(fmaf(x0, wr0.z, fmaf(x1, wr1.z, fmaf(x2, wr2.z, bb0.z))), 0.f);
                float hw = fmaxf(fmaf(x0, wr0.w, fmaf(x1, wr1.w, fmaf(x2, wr2.w, bb0.w))), 0.f);
                short4 hv = make_short4((short)f2bf(hx), (short)f2bf(hy),
                                        (short)f2bf(hz), (short)f2bf(hw));
                *(short4*)&cur[hsw(pt, j0)] = hv;
            }
        }
        barrier_nd();

        // ---- 7 hidden layers, W hi/lo x H bf16, 2-stage ping-pong + x-layer prefetch ----
        for (int l = 0; l < NHID; ++l) {
            const int L = M * 7 + l;
            const int Ln = (L + 1 < 14) ? (L + 1) : 13;
            f32x4 acc[NPT];
            {
                float4 b4 = *(const float4*)&bh[l * F + wv * 16 + kg * 4];
#pragma unroll
                for (int p = 0; p < NPT; ++p)
                    acc[p] = (f32x4){b4.x, b4.y, b4.z, b4.w};
            }

            LH(hA, 0) LH(hB, 1)
            __builtin_amdgcn_sched_barrier(0);
            MM(wAhi, wAlo, hA)              // s0
            LW(wAhi, wAlo, L, 2) LH(hA, 2)
            __builtin_amdgcn_sched_barrier(0);
            MM(wBhi, wBlo, hB)              // s1
            LW(wBhi, wBlo, L, 3) LH(hB, 3)
            __builtin_amdgcn_sched_barrier(0);
            MM(wAhi, wAlo, hA)              // s2
            LW(wAhi, wAlo, Ln, 0)           // prefetch next layer s0
            __builtin_amdgcn_sched_barrier(0);
            MM(wBhi, wBlo, hB)              // s3
            LW(wBhi, wBlo, Ln, 1)           // prefetch next layer s1

            // ReLU + bf16 + swizzled write
#pragma unroll
            for (int p = 0; p < NPT; ++p) {
                float v0 = fmaxf(acc[p][0], 0.f), v1 = fmaxf(acc[p][1], 0.f);
                float v2 = fmaxf(acc[p][2], 0.f), v3 = fmaxf(acc[p][3], 0.f);
                short4 hv = make_short4((short)f2bf(v0), (short)f2bf(v1),
                                        (short)f2bf(v2), (short)f2bf(v3));
                *(short4*)&nxt[hsw(p * 16 + arow, wv * 16 + kg * 4)] = hv;
            }
            barrier_nd();
            unsigned short* tsw = cur; cur = nxt; nxt = tsw;
        }

        // ---- final layer 128->3: 240 threads, full-k, 4 rotating accs ----
        if (tid < 240) {
            int pt = tid / 3;
            int c = tid - 3 * pt;
            const float* wl = wlt + M * 384 + c * 128;
            float a0 = 0.f, a1 = 0.f, a2 = 0.f, a3 = 0.f;
#pragma unroll
            for (int q = 0; q < 16; ++q) {
                short8v h8 = *(const short8v*)&cur[hsw(pt, q * 8)];
                float4 wa = *(const float4*)(wl + q * 8);
                float4 wb = *(const float4*)(wl + q * 8 + 4);
                a0 = fmaf(bf2f((unsigned short)h8[0]), wa.x, a0);
                a1 = fmaf(bf2f((unsigned short)h8[1]), wa.y, a1);
                a2 = fmaf(bf2f((unsigned short)h8[2]), wa.z, a2);
                a3 = fmaf(bf2f((unsigned short)h8[3]), wa.w, a3);
                a0 = fmaf(bf2f((unsigned short)h8[4]), wb.x, a0);
                a1 = fmaf(bf2f((unsigned short)h8[5]), wb.y, a1);
                a2 = fmaf(bf2f((unsigned short)h8[6]), wb.z, a2);
                a3 = fmaf(bf2f((unsigned short)h8[7]), wb.w, a3);
            }
            float flow = ((a0 + a1) + (a2 + a3)) + bl[c];
            int gp = p0 + pt;
            int cp = gp < N ? gp : N - 1;
            if (M == 0) {
                float val = pc0[cp * 3 + c] + flow;
                Al[pt][c] = val;
                if (gp < N) Aout[gp * 3 + c] = val;
            } else {
                float val = Al[pt][c] - flow;
                Cl[pt][c] = val;
                if (gp < N) Cout[gp * 3 + c] = val;
            }
        }
        barrier_nd();
    }
#undef LW
#undef LH
#undef MM

    // ---- epilogue: grid counts for all 4 clouds (block's own points) ----
    if (tid < BP) {
        int gp = p0 + tid;
        if (gp < N) {
            atomicAdd(&counts[1 * GM3 + cell_of(Al[tid][0], Al[tid][1], Al[tid][2])], 1);
            atomicAdd(&counts[3 * GM3 + cell_of(Cl[tid][0], Cl[tid][1], Cl[tid][2])], 1);
            atomicAdd(&counts[0 * GM3 + cell_of(pc1[gp * 3 + 0], pc1[gp * 3 + 1], pc1[gp * 3 + 2])], 1);
            atomicAdd(&counts[2 * GM3 + cell_of(pc0[gp * 3 + 0], pc0[gp * 3 + 1], pc0[gp * 3 + 2])], 1);
        }
    }
}

// ---------------- grid build ----------------
__device__ inline const float* cloud_ptr(int g, const float* g0, const float* g1,
                                         const float* g2, const float* g3)
{
    return g == 0 ? g0 : (g == 1 ? g1 : (g == 2 ? g2 : g3));
}

__global__ __launch_bounds__(256) void scan1(
    const int* __restrict__ counts, int* __restrict__ offs, int* __restrict__ bsum)
{
    int tid = threadIdx.x;
    int i = blockIdx.x * 256 + tid;
    int v = counts[i];
    __shared__ int s[256];
    s[tid] = v;
    __syncthreads();
#pragma unroll
    for (int off = 1; off < 256; off <<= 1) {
        int t = (tid >= off) ? s[tid - off] : 0;
        __syncthreads();
        s[tid] += t;
        __syncthreads();
    }
    offs[i] = s[tid] - v;           // exclusive
    if (tid == 255) bsum[blockIdx.x] = s[255];
}

// scan2+scan3 fused: per-block segment prefix of bsum (SCAN_BLKS=128 <= 256),
// add to offs, re-zero counts (cursors for grid_fill)
__global__ __launch_bounds__(256) void scan23(
    int* __restrict__ offs, const int* __restrict__ bsum, int* __restrict__ counts)
{
    int seg = blockIdx.x / SCAN_BLKS;
    int pos = blockIdx.x - seg * SCAN_BLKS;
    const int* bs = bsum + seg * SCAN_BLKS;
    int t = threadIdx.x;
    int v = (t < pos) ? bs[t] : 0;
    __shared__ int red[4];
#pragma unroll
    for (int o = 32; o > 0; o >>= 1) v += __shfl_down(v, o, 64);
    if ((t & 63) == 0) red[t >> 6] = v;
    __syncthreads();
    int prefix = red[0] + red[1] + red[2] + red[3];
    int i = blockIdx.x * 256 + t;
    offs[i] += prefix;
    counts[i] = 0;
}

__global__ __launch_bounds__(256) void grid_fill(
    const float* __restrict__ B, const float* __restrict__ A,
    const float* __restrict__ D, const float* __restrict__ C,
    const int* __restrict__ offs, int* __restrict__ counts,
    float4* __restrict__ pts, int n)
{
    int g = blockIdx.y;
    const float* P = cloud_ptr(g, B, A, D, C);
    int i = blockIdx.x * 256 + threadIdx.x;
    if (i < n) {
        float x = P[i * 3 + 0], y = P[i * 3 + 1], z = P[i * 3 + 2];
        int c = g * GM3 + cell_of(x, y, z);
        int slot = offs[c] + atomicAdd(&counts[c], 1);
        pts[(size_t)g * n + slot] = make_float4(x, y, z, 0.f);
    }
}

// ---------------- block sum helper ----------------
__device__ inline float block_sum256(float v)
{
    __shared__ float sws[4];
#pragma unroll
    for (int o = 32; o > 0; o >>= 1) v += __shfl_down(v, o, 64);
    int w = threadIdx.x >> 6;
    if ((threadIdx.x & 63) == 0) sws[w] = v;
    __syncthreads();
    if (threadIdx.x == 0) v = sws[0] + sws[1] + sws[2] + sws[3];
    return v;
}

// cell-sorted truncated NN search: queries read from the (already cell-sorted)
// pts array of the query cloud (gq = d^1); 2 threads per query split the 9
// neighbor rows 4/5; fmin-combined via LDS; block sum + fused final reduction.
__global__ __launch_bounds__(256) void grid_search(
    const int* __restrict__ offs, const int* __restrict__ counts,
    const float4* __restrict__ pts, float* __restrict__ partials,
    unsigned int* __restrict__ done, float* __restrict__ out, float inv, int n)
{
    const int d = blockIdx.y;
    const float4* Qs = pts + (size_t)(d ^ 1) * n;   // sorted query cloud
    const float4* P  = pts + (size_t)d * n;         // sorted target cloud
    const int* ofs = offs + (size_t)d * GM3;
    const int* cnt = counts + (size_t)d * GM3;

    const int tid = threadIdx.x;
    const int ql = tid & (BQ - 1);
    const int half = tid >> 7;          // 0: rows 0-3, 1: rows 4-8
    const int i = blockIdx.x * BQ + ql;

    float mn = 3.4e38f;
    if (i < n) {
        float4 q = Qs[i];
        int cx = min(max((int)floorf((q.x - GLO) * GINV), 0), GM - 1);
        int cy = min(max((int)floorf((q.y - GLO) * GINV), 0), GM - 1);
        int cz = min(max((int)floorf((q.z - GLO) * GINV), 0), GM - 1);
        int xa = max(cx - 1, 0), xb = min(cx + 1, GM - 1);
        int r0 = half * 4;

        int o[5], e[5];
#pragma unroll
        for (int r = 0; r < 5; ++r) {
            o[r] = 0; e[r] = 0;
            bool act = half ? true : (r < 4);
            if (act) {
                int rr = r0 + r;                 // 0..3 or 4..8
                int dz = rr / 3, dy = rr - dz * 3;
                int z = cz + dz - 1;
                int y = cy + dy - 1;
                if ((unsigned)z < GM && (unsigned)y < GM) {
                    int rowbase = (z * GM + y) * GM;
                    o[r] = ofs[rowbase + xa];
                    e[r] = ofs[rowbase + xb] + cnt[rowbase + xb];
                }
            }
        }
#pragma unroll
        for (int r = 0; r < 5; ++r) {
            for (int k = o[r]; k < e[r]; ++k) {
                float4 p = P[k];
                float ddx = q.x - p.x, ddy = q.y - p.y, ddz = q.z - p.z;
                mn = fminf(mn, fmaf(ddx, ddx, fmaf(ddy, ddy, ddz * ddz)));
            }
        }
    }

    __shared__ float m0[BQ];
    if (half == 0) m0[ql] = mn;
    __syncthreads();
    float val = 0.f;
    if (half == 1 && i < n) {
        float m = fminf(mn, m0[ql]);
        val = (m < TRUNC_) ? m : 0.f;
    }
    float bs = block_sum256(val);

    __shared__ int lastflag;
    if (threadIdx.x == 0) {
        atomicExch(&partials[(size_t)d * gridDim.x + blockIdx.x], bs);
        __threadfence();
        unsigned v = atomicAdd(done, 1u);
        lastflag = (v == (unsigned)(NGRID * gridDim.x - 1)) ? 1 : 0;
    }
    __syncthreads();
    if (lastflag) {
        int NPt = NGRID * gridDim.x;
        float s = 0.f;
        for (int j = threadIdx.x; j < NPt; j += 256)
            s += atomicAdd(&partials[j], 0.0f);   // device-scope read
        __syncthreads();
        float tot = block_sum256(s);
        if (threadIdx.x == 0) out[0] = tot * inv;
    }
}

// ---------------- launch ----------------
extern "C" void kernel_launch(void* const* d_in, const int* in_sizes, int n_in,
                              void* d_out, int out_size, void* d_ws, size_t ws_size,
                              hipStream_t stream)
{
    const float* pc0 = (const float*)d_in[0];
    const float* pc1 = (const float*)d_in[1];
    const float* W0  = (const float*)d_in[2];
    const float* b0  = (const float*)d_in[3];
    const float* Wh  = (const float*)d_in[4];
    const float* bh  = (const float*)d_in[5];
    const float* Wl  = (const float*)d_in[6];
    const float* bl  = (const float*)d_in[7];
    const float* W0i = (const float*)d_in[8];
    const float* b0i = (const float*)d_in[9];
    const float* Whi = (const float*)d_in[10];
    const float* bhi = (const float*)d_in[11];
    const float* Wli = (const float*)d_in[12];
    const float* bli = (const float*)d_in[13];
    float* out = (float*)d_out;

    const int N = in_sizes[0] / 3;   // 20000

    // ws layout (byte offsets)
    char* base = (char*)d_ws;
    float*  A        = (float*)(base + 0);               // 240000
    float*  C        = (float*)(base + 240000);          // 240000
    int*    counts   = (int*)  (base + 480000);          // 524288
    int*    offs     = (int*)  (base + 1004288);         // 524288
    int*    bsum     = (int*)  (base + 1528576);         // 4096
    float4* pts      = (float4*)(base + 1532672);        // 1280000
    float*  partials = (float*)(base + 2812672);         // 4096
    unsigned int* done = (unsigned int*)(base + 2816768);// 16
    unsigned short* whp = (unsigned short*)(base + 2816784); // 458752
    unsigned short* wlp = (unsigned short*)(base + 3275536); // 458752
    float*  wlt      = (float*)(base + 3734288);         // 3072

    const int PB = (N + 255) / 256;        // 79
    const int QB = (N + BQ - 1) / BQ;      // 157 search blocks per direction

    // prep: pack weights + WlT + zero counts + zero done-counter
    hipLaunchKernelGGL(prep_kernel, dim3(PACKB + ZB + 1), dim3(256), 0, stream,
                       Wh, Whi, Wl, Wli, whp, wlp, wlt, counts, done);

    int mlpg = (N + BP - 1) / BP;  // 250
    hipLaunchKernelGGL(mlp_fused_kernel, dim3(mlpg), dim3(512), 0, stream,
                       pc0, pc1, W0, b0, W0i, b0i, whp, wlp, bh, bhi,
                       wlt, bl, bli, A, C, counts, N);

    // grids: g0=pc1, g1=A, g2=pc0, g3=C (counts already done in mlp epilogue)
    hipLaunchKernelGGL(scan1, dim3(ZB), dim3(256), 0, stream, counts, offs, bsum);
    hipLaunchKernelGGL(scan23, dim3(ZB), dim3(256), 0, stream, offs, bsum, counts);
    hipLaunchKernelGGL(grid_fill, dim3(PB, NGRID), dim3(256), 0, stream,
                       pc1, A, pc0, C, offs, counts, pts, N);

    // cell-sorted truncated NN search + block sums + fused final reduce
    hipLaunchKernelGGL(grid_search, dim3(QB, NGRID), dim3(256), 0, stream,
                       offs, counts, pts, partials, done, out,
                       1.0f / (float)N, N);
}